// Round 7
// baseline (276.084 us; speedup 1.0000x reference)
//
#include <hip/hip_runtime.h>
#include <hip/hip_bf16.h>

// Problem constants
#define BATCH 2
#define LSEQ 2048
#define DMODEL 1024
#define NH 16
#define DQK 16
#define DV 64
#define FDIM 273            // 1 + 16 + 256
#define CHUNK 128
#define NCH (LSEQ / CHUNK)  // 16 chunks per batch row
#define ROWS (BATCH * LSEQ) // 4096
#define NBH (BATCH * NH)    // 32
#define NBC (NBH * NCH)     // 512 (b,h,chunk) units
#define C2 0.17677669529663687f  // 1/(4*sqrt(2))

typedef short bf16x8 __attribute__((ext_vector_type(8)));
typedef float f32x4 __attribute__((ext_vector_type(4)));

__device__ __forceinline__ unsigned short f2bf(float f) {
  __hip_bfloat16 h = __float2bfloat16(f);
  unsigned short u; __builtin_memcpy(&u, &h, 2); return u;
}
__device__ __forceinline__ float bf2f(unsigned short u) {
  unsigned int v = (unsigned int)u << 16; float f; __builtin_memcpy(&f, &v, 4); return f;
}

// ---------------------------------------------------------------------------
// fp32 -> bf16 elementwise cast (float4 / ushort4 vectorized)
// ---------------------------------------------------------------------------
__global__ __launch_bounds__(256) void cast4(const float* __restrict__ in,
                                             unsigned short* __restrict__ out, int n4) {
  int i = blockIdx.x * 256 + threadIdx.x;
  if (i >= n4) return;
  float4 v = ((const float4*)in)[i];
  ushort4 o = {f2bf(v.x), f2bf(v.y), f2bf(v.z), f2bf(v.w)};
  ((ushort4*)out)[i] = o;
}

// ---------------------------------------------------------------------------
// W (KxN fp32, row-major) -> Wt (NxK bf16, row-major).  32x32 LDS tile.
// ---------------------------------------------------------------------------
__global__ __launch_bounds__(256) void transpose_cast(
    const float* __restrict__ W, unsigned short* __restrict__ Wt, int K, int N) {
  __shared__ float t[32][33];
  const int kb = blockIdx.y * 32, nb = blockIdx.x * 32;
  const int tx = threadIdx.x & 31, ty4 = (threadIdx.x >> 5) * 4;
#pragma unroll
  for (int r = 0; r < 4; r++)
    t[ty4 + r][tx] = W[(size_t)(kb + ty4 + r) * N + nb + tx];
  __syncthreads();
#pragma unroll
  for (int r = 0; r < 4; r++)
    Wt[(size_t)(nb + ty4 + r) * K + kb + tx] = f2bf(t[tx][ty4 + r]);
}

// ---------------------------------------------------------------------------
// MFMA GEMM (m97 pattern): C(MxN fp32) = A(MxK bf16) @ Bt(NxK bf16)^T.
// 128x128 tile, BK=32, 256 threads = 4 waves, each wave a 64x64 quadrant.
// ---------------------------------------------------------------------------
__global__ __launch_bounds__(256) void gemm_mfma(
    const unsigned short* __restrict__ A, const unsigned short* __restrict__ Bt,
    float* __restrict__ C, int M, int N, int K) {
  __shared__ unsigned short As[512 * 8];
  __shared__ unsigned short Bs[512 * 8];
  const int tid = threadIdx.x;
  const int bm = blockIdx.y * 128, bn = blockIdx.x * 128;
  const int lane = tid & 63;
  const int w = tid >> 6;
  const int qr = (w >> 1) * 64, qc = (w & 1) * 64;
  f32x4 acc[4][4] = {};

  for (int k0 = 0; k0 < K; k0 += 32) {
#pragma unroll
    for (int j = 0; j < 4; ++j) {
      int c = j * 256 + tid;
      int cc = c & 511;
      int row = ((cc >> 6) << 4) + (cc & 15);
      int kh = (cc >> 4) & 3;
      const unsigned short* gp;
      unsigned short* lp;
      if (c < 512) { gp = A  + (size_t)(bm + row) * K + k0 + kh * 8; lp = As + cc * 8; }
      else         { gp = Bt + (size_t)(bn + row) * K + k0 + kh * 8; lp = Bs + cc * 8; }
      __builtin_amdgcn_global_load_lds(
          (const __attribute__((address_space(1))) unsigned int*)(const void*)gp,
          (__attribute__((address_space(3))) unsigned int*)lp, 16, 0, 0);
    }
    __syncthreads();
    bf16x8 a[4], b[4];
#pragma unroll
    for (int i = 0; i < 4; ++i) {
      a[i] = *(const bf16x8*)(As + ((qr >> 4) + i) * 512 + lane * 8);
      b[i] = *(const bf16x8*)(Bs + ((qc >> 4) + i) * 512 + lane * 8);
    }
#pragma unroll
    for (int i = 0; i < 4; ++i)
#pragma unroll
      for (int jj = 0; jj < 4; ++jj)
        acc[i][jj] = __builtin_amdgcn_mfma_f32_16x16x32_bf16(a[i], b[jj], acc[i][jj], 0, 0, 0);
    __syncthreads();
  }
  const int cn = lane & 15, r0 = (lane >> 4) * 4;
#pragma unroll
  for (int i = 0; i < 4; ++i)
#pragma unroll
    for (int jj = 0; jj < 4; ++jj) {
      size_t base = (size_t)(bm + qr + i * 16 + r0) * N + bn + qc + jj * 16 + cn;
#pragma unroll
      for (int r = 0; r < 4; ++r) C[base + (size_t)r * N] = acc[i][jj][r];
    }
}

// ---------------------------------------------------------------------------
// Pass 1 (MFMA): S_c = Kf^T[288x128] @ [V|1|pad][128x80] per (b,h,chunk).
// Kf A-fragments generated on the fly (bf16), double-buffered.  Output S in
// bf16 (it is consumed as bf16 in the P path anyway; halves write traffic).
// ---------------------------------------------------------------------------
__global__ __launch_bounds__(256) void chunk_sums_mfma(
    const float* __restrict__ qkb, const float* __restrict__ vbuf,
    unsigned short* __restrict__ Sb16, float* __restrict__ ubuf) {
  const int c = blockIdx.x, bh = blockIdx.y;
  const int b = bh >> 4, h = bh & 15;
  const int tid = threadIdx.x;
  const int lane = tid & 63, w = tid >> 6;
  const int row0 = b * LSEQ + c * CHUNK;

  __shared__ float ksT[16 * 132];   // k transposed [d][i], stride 132
  __shared__ short Vp[20 * 512];    // B-operand [V | 1 | 0-pad]
  __shared__ short Kf[2][18 * 512]; // A-operand dbuf (one 32-k slice)

  {
    int i = tid >> 1, d0 = (tid & 1) * 8;
    const float* src = qkb + (size_t)(row0 + i) * 512 + 256 + h * 16 + d0;
    float4 v0 = *(const float4*)src;
    float4 v1 = *(const float4*)(src + 4);
    ksT[(d0 + 0) * 132 + i] = v0.x; ksT[(d0 + 1) * 132 + i] = v0.y;
    ksT[(d0 + 2) * 132 + i] = v0.z; ksT[(d0 + 3) * 132 + i] = v0.w;
    ksT[(d0 + 4) * 132 + i] = v1.x; ksT[(d0 + 5) * 132 + i] = v1.y;
    ksT[(d0 + 6) * 132 + i] = v1.z; ksT[(d0 + 7) * 132 + i] = v1.w;
  }
  for (int t = tid; t < 1280; t += 256) {
    int e, jg;
    if (t < 1024) { e = t & 63; jg = t >> 6; }
    else { int x = t - 1024; e = 64 + (x & 15); jg = x >> 4; }
    bf16x8 v8;
#pragma unroll
    for (int jj = 0; jj < 8; jj++) {
      float val;
      if (e < 64) val = vbuf[(size_t)(row0 + jg * 8 + jj) * (NH * DV) + h * DV + e];
      else val = (e == 64) ? 1.0f : 0.0f;
      v8[jj] = (short)f2bf(val);
    }
    *(bf16x8*)(Vp + ((e >> 4) * 4 + (jg >> 2)) * 512 + ((jg & 3) * 16 + (e & 15)) * 8) = v8;
  }
  __syncthreads();

  auto gen = [&](int kt) {
    for (int o = tid; o < 1152; o += 256) {
      int mt = o >> 6, w6 = o & 63;
      int kh = w6 >> 4, m = w6 & 15;
      int f = mt * 16 + m;
      int i0 = kt * 32 + kh * 8;
      bf16x8 v8;
      if (f == 0) {
#pragma unroll
        for (int j = 0; j < 8; j++) v8[j] = (short)0x3F80;
      } else if (f < 17) {
        const float* ka = &ksT[(f - 1) * 132 + i0];
        float4 a0 = *(const float4*)ka, a1 = *(const float4*)(ka + 4);
        v8[0] = (short)f2bf(0.5f * a0.x); v8[1] = (short)f2bf(0.5f * a0.y);
        v8[2] = (short)f2bf(0.5f * a0.z); v8[3] = (short)f2bf(0.5f * a0.w);
        v8[4] = (short)f2bf(0.5f * a1.x); v8[5] = (short)f2bf(0.5f * a1.y);
        v8[6] = (short)f2bf(0.5f * a1.z); v8[7] = (short)f2bf(0.5f * a1.w);
      } else if (f < FDIM) {
        int ix = f - 17;
        const float* ka = &ksT[(ix >> 4) * 132 + i0];
        const float* kb2 = &ksT[(ix & 15) * 132 + i0];
        float4 a0 = *(const float4*)ka, a1 = *(const float4*)(ka + 4);
        float4 b0 = *(const float4*)kb2, b1 = *(const float4*)(kb2 + 4);
        v8[0] = (short)f2bf(C2 * a0.x * b0.x); v8[1] = (short)f2bf(C2 * a0.y * b0.y);
        v8[2] = (short)f2bf(C2 * a0.z * b0.z); v8[3] = (short)f2bf(C2 * a0.w * b0.w);
        v8[4] = (short)f2bf(C2 * a1.x * b1.x); v8[5] = (short)f2bf(C2 * a1.y * b1.y);
        v8[6] = (short)f2bf(C2 * a1.z * b1.z); v8[7] = (short)f2bf(C2 * a1.w * b1.w);
      } else {
#pragma unroll
        for (int j = 0; j < 8; j++) v8[j] = 0;
      }
      *(bf16x8*)(Kf[kt & 1] + mt * 512 + (kh * 16 + m) * 8) = v8;
    }
  };

  gen(0);
  __syncthreads();

  f32x4 acc[5][5] = {};
  const int nmt = (w < 2) ? 5 : 4;
  for (int kt = 0; kt < 4; kt++) {
    if (kt < 3) gen(kt + 1);
    bf16x8 bv[5];
#pragma unroll
    for (int nt = 0; nt < 5; nt++)
      bv[nt] = *(const bf16x8*)(Vp + (nt * 4 + kt) * 512 + lane * 8);
#pragma unroll
    for (int t2 = 0; t2 < 5; t2++) {
      if (t2 < nmt) {
        int mt = w + t2 * 4;
        bf16x8 av = *(const bf16x8*)(Kf[kt & 1] + mt * 512 + lane * 8);
#pragma unroll
        for (int nt = 0; nt < 5; nt++)
          acc[t2][nt] = __builtin_amdgcn_mfma_f32_16x16x32_bf16(av, bv[nt], acc[t2][nt], 0, 0, 0);
      }
    }
    __syncthreads();
  }

  const int cl = lane & 15, r0q = (lane >> 4) * 4;
  const size_t sbase = ((size_t)bh * NCH + c) * FDIM;
#pragma unroll
  for (int t2 = 0; t2 < 5; t2++) {
    if (t2 < nmt) {
      int mt = w + t2 * 4;
#pragma unroll
      for (int reg = 0; reg < 4; reg++) {
        int f = mt * 16 + r0q + reg;
        if (f < FDIM) {
#pragma unroll
          for (int nt = 0; nt < 4; nt++)
            Sb16[(sbase + f) * DV + nt * 16 + cl] = f2bf(acc[t2][nt][reg]);
          if (cl == 0) ubuf[sbase + f] = acc[t2][4][reg];
        }
      }
    }
  }
}

// ---------------------------------------------------------------------------
// Pass 2: exclusive prefix over chunks, emitted DIRECTLY in bf16 MFMA
// B-fragment layout: PG[((bh*16+c)*45 + kt*5 + nt)*512 + (kh*16 + n)*8 + (f&7)]
// covering [P | u | 0-pad] (N=80, K=288, zero-padded).  attn stages it by DMA.
// grid (36 f-groups of 8, 32 bh) x 128 threads (e = tid < 80 active).
// ---------------------------------------------------------------------------
__global__ __launch_bounds__(128) void prefix_scan_frag(
    const unsigned short* __restrict__ Sb16, const float* __restrict__ ubuf,
    unsigned short* __restrict__ PG) {
  const int g = blockIdx.x, bh = blockIdx.y;
  const int e = threadIdx.x;
  if (e >= 80) return;
  const int f0 = g * 8;
  const int kt = f0 >> 5, kh = (f0 >> 3) & 3;
  const int nt = e >> 4, n = e & 15;
  float run[8] = {0.f, 0.f, 0.f, 0.f, 0.f, 0.f, 0.f, 0.f};
  for (int cc = 0; cc < NCH; cc++) {
    bf16x8 v8;
#pragma unroll
    for (int j = 0; j < 8; j++) v8[j] = (short)f2bf(run[j]);
    *(bf16x8*)(PG + ((size_t)(bh * NCH + cc) * 45 + kt * 5 + nt) * 512 +
               (kh * 16 + n) * 8) = v8;
    const size_t sb = ((size_t)bh * NCH + cc) * FDIM;
    if (e < 64) {
#pragma unroll
      for (int j = 0; j < 8; j++) {
        int f = f0 + j;
        if (f < FDIM) run[j] += bf2f(Sb16[(sb + f) * DV + e]);
      }
    } else if (e == 64) {
#pragma unroll
      for (int j = 0; j < 8; j++) {
        int f = f0 + j;
        if (f < FDIM) run[j] += ubuf[sb + f];
      }
    }
  }
}

// ---------------------------------------------------------------------------
// Pass 3 (MFMA): per-(b,h,chunk) outputs -> bf16 y.
// LDS union U (77 KB, 2 blocks/CU):
//   phase 1: Qb U[0..4095], Kb U[4096..8191]; epi-> Am U[8192..24575]
//   phase 2: Vp U[24576..34815]; qsB (bf16 q, stride 17) U[36864..39039]
//   Qf gen : full 128x288 Qf A-fragments -> U[0..36863] (once)
//   ft loop: Pp (5 chunks) DMA'd from PG -> U[36864..39423]
// ---------------------------------------------------------------------------
__global__ __launch_bounds__(256) void attn_mfma(
    const float* __restrict__ qkb, const float* __restrict__ vbuf,
    const unsigned short* __restrict__ PG, unsigned short* __restrict__ ybuf) {
  const int c = blockIdx.x, bh = blockIdx.y;
  const int b = bh >> 4, h = bh & 15;
  const int tid = threadIdx.x;
  const int lane = tid & 63, w = tid >> 6;
  const int row0 = b * LSEQ + c * CHUNK;

  __shared__ short U[39424];
  __shared__ float denL[128];
  unsigned short* Uu = (unsigned short*)U;

  // ---- stage qsB (bf16 q rows, stride 17 -> conflict-free gathers) ----
  {
    int i = tid >> 1, d0 = (tid & 1) * 8;
    const float* src = qkb + (size_t)(row0 + i) * 512 + h * 16 + d0;
    float4 v0 = *(const float4*)src;
    float4 v1 = *(const float4*)(src + 4);
    unsigned short* qd = Uu + 36864 + i * 17 + d0;
    qd[0] = f2bf(v0.x); qd[1] = f2bf(v0.y); qd[2] = f2bf(v0.z); qd[3] = f2bf(v0.w);
    qd[4] = f2bf(v1.x); qd[5] = f2bf(v1.y); qd[6] = f2bf(v1.z); qd[7] = f2bf(v1.w);
  }
  // ---- stage Qb, Kb (bf16 fragments, K padded to 32 with zeros) ----
  for (int t = tid; t < 1024; t += 256) {
    int isK = t >> 9;
    int tt = t & 511;
    int i = tt >> 2, kh = tt & 3;
    bf16x8 v8 = {0, 0, 0, 0, 0, 0, 0, 0};
    if (kh < 2) {
      const float* src = qkb + (size_t)(row0 + i) * 512 + isK * 256 + h * 16 + kh * 8;
      float4 a = *(const float4*)src;
      float4 bq = *(const float4*)(src + 4);
      v8[0] = (short)f2bf(a.x);  v8[1] = (short)f2bf(a.y);
      v8[2] = (short)f2bf(a.z);  v8[3] = (short)f2bf(a.w);
      v8[4] = (short)f2bf(bq.x); v8[5] = (short)f2bf(bq.y);
      v8[6] = (short)f2bf(bq.z); v8[7] = (short)f2bf(bq.w);
    }
    *(bf16x8*)(U + isK * 4096 + (i >> 4) * 512 + (kh * 16 + (i & 15)) * 8) = v8;
  }
  __syncthreads();

  // ---- phase 1: S = Q K^T -> poly+mask -> Am (A-fragment layout) ----
  {
    bf16x8 aq[2];
#pragma unroll
    for (int mi = 0; mi < 2; mi++)
      aq[mi] = *(const bf16x8*)(U + (w * 2 + mi) * 512 + lane * 8);
    f32x4 S[2][8] = {};
#pragma unroll
    for (int nt = 0; nt < 8; nt++) {
      bf16x8 bk = *(const bf16x8*)(U + 4096 + nt * 512 + lane * 8);
#pragma unroll
      for (int mi = 0; mi < 2; mi++)
        S[mi][nt] = __builtin_amdgcn_mfma_f32_16x16x32_bf16(aq[mi], bk, S[mi][nt], 0, 0, 0);
    }
    __syncthreads();  // Qb/Kb reads done before Am overwrites U[8192..]
    const int cl = lane & 15, r0q = (lane >> 4) * 4;
#pragma unroll
    for (int mi = 0; mi < 2; mi++)
#pragma unroll
      for (int nt = 0; nt < 8; nt++)
#pragma unroll
        for (int reg = 0; reg < 4; reg++) {
          int i = (w * 2 + mi) * 16 + r0q + reg;
          int j = nt * 16 + cl;
          float s = S[mi][nt][reg];
          float aij = (j <= i) ? fmaf(s, fmaf(s, 0.03125f, 0.25f), 1.0f) : 0.0f;
          U[8192 + ((i >> 4) * 4 + (j >> 5)) * 512 +
            (((j >> 3) & 3) * 16 + (i & 15)) * 8 + (j & 7)] = (short)f2bf(aij);
        }
  }
  // ---- stage Vp = [V | 1 | 0-pad] (B-operand, N=80, K=128) ----
  for (int t = tid; t < 1280; t += 256) {
    int e, jg;
    if (t < 1024) { e = t & 63; jg = t >> 6; }
    else { int x = t - 1024; e = 64 + (x & 15); jg = x >> 4; }
    bf16x8 v8;
#pragma unroll
    for (int jj = 0; jj < 8; jj++) {
      float val;
      if (e < 64) val = vbuf[(size_t)(row0 + jg * 8 + jj) * (NH * DV) + h * DV + e];
      else val = (e == 64) ? 1.0f : 0.0f;
      v8[jj] = (short)f2bf(val);
    }
    *(bf16x8*)(U + 24576 + ((e >> 4) * 4 + (jg >> 2)) * 512 +
               ((jg & 3) * 16 + (e & 15)) * 8) = v8;
  }
  __syncthreads();

  // ---- phase 2: Y = A · Vp ----
  f32x4 Y[2][5] = {};
#pragma unroll
  for (int kc = 0; kc < 4; kc++) {
    bf16x8 a2[2];
#pragma unroll
    for (int mi = 0; mi < 2; mi++)
      a2[mi] = *(const bf16x8*)(U + 8192 + ((w * 2 + mi) * 4 + kc) * 512 + lane * 8);
#pragma unroll
    for (int nt = 0; nt < 5; nt++) {
      bf16x8 b2 = *(const bf16x8*)(U + 24576 + (nt * 4 + kc) * 512 + lane * 8);
#pragma unroll
      for (int mi = 0; mi < 2; mi++)
        Y[mi][nt] = __builtin_amdgcn_mfma_f32_16x16x32_bf16(a2[mi], b2, Y[mi][nt], 0, 0, 0);
    }
  }
  __syncthreads();  // phase-2 reads done; U[0..36863] free for Qf

  // ---- Qf gen: full 128x288 A-fragments into U[0..36863] (once) ----
#pragma unroll 2
  for (int iter = 0; iter < 18; iter++) {
    int gv = iter * 256 + tid;
    int kt = gv >> 9;
    int w9 = gv & 511;
    int row = ((w9 >> 6) << 4) + (w9 & 15);
    int kh = (w9 >> 4) & 3;
    const unsigned short* qr = Uu + 36864 + row * 17;
    bf16x8 v8;
#pragma unroll
    for (int j = 0; j < 8; j++) {
      int f = kt * 32 + kh * 8 + j;
      float qf;
      if (f == 0) qf = 1.0f;
      else if (f < 17) qf = 0.5f * bf2f(qr[f - 1]);
      else if (f < FDIM) {
        int ix = f - 17;
        qf = C2 * bf2f(qr[ix >> 4]) * bf2f(qr[ix & 15]);
      } else qf = 0.0f;
      v8[j] = (short)f2bf(qf);
    }
    *(bf16x8*)(U + (size_t)gv * 8) = v8;
  }

  // ---- phase 3: Y += Qf · [P|u], 9 k-tiles; Pp staged by pure DMA ----
  const size_t pgb = ((size_t)bh * NCH + c) * 45 * 512;
  for (int ft = 0; ft < 9; ft++) {
    __syncthreads();  // prior Pp readers done (ft=0: Qf writes/qsB reads done)
    {
      const unsigned short* gpb = PG + pgb + (size_t)ft * 2560;
      __builtin_amdgcn_global_load_lds(
          (const __attribute__((address_space(1))) unsigned int*)(const void*)(gpb + tid * 8),
          (__attribute__((address_space(3))) unsigned int*)(Uu + 36864 + tid * 8), 16, 0, 0);
      if (tid < 64) {
        __builtin_amdgcn_global_load_lds(
            (const __attribute__((address_space(1))) unsigned int*)(const void*)(gpb + (256 + tid) * 8),
            (__attribute__((address_space(3))) unsigned int*)(Uu + 36864 + (256 + tid) * 8), 16, 0, 0);
      }
    }
    __syncthreads();  // DMA landed
    bf16x8 a3[2];
#pragma unroll
    for (int mi = 0; mi < 2; mi++)
      a3[mi] = *(const bf16x8*)(U + (size_t)ft * 4096 + (w * 2 + mi) * 512 + lane * 8);
#pragma unroll
    for (int nt = 0; nt < 5; nt++) {
      bf16x8 b3 = *(const bf16x8*)(U + 36864 + nt * 512 + lane * 8);
#pragma unroll
      for (int mi = 0; mi < 2; mi++)
        Y[mi][nt] = __builtin_amdgcn_mfma_f32_16x16x32_bf16(a3[mi], b3, Y[mi][nt], 0, 0, 0);
    }
  }

  // ---- epilogue: den from ones column (nt=4, col 0), scale, store bf16 ----
  const int cl = lane & 15, r0q = (lane >> 4) * 4;
  if (cl == 0) {
#pragma unroll
    for (int mi = 0; mi < 2; mi++)
#pragma unroll
      for (int reg = 0; reg < 4; reg++)
        denL[(w * 2 + mi) * 16 + r0q + reg] = Y[mi][4][reg];
  }
  __syncthreads();
#pragma unroll
  for (int mi = 0; mi < 2; mi++) {
    float invd[4];
#pragma unroll
    for (int reg = 0; reg < 4; reg++)
      invd[reg] = 1.0f / (denL[(w * 2 + mi) * 16 + r0q + reg] + 1e-12f);
#pragma unroll
    for (int nt = 0; nt < 4; nt++)
#pragma unroll
      for (int reg = 0; reg < 4; reg++) {
        int i = (w * 2 + mi) * 16 + r0q + reg;
        int e = nt * 16 + cl;
        ybuf[(size_t)(row0 + i) * (NH * DV) + h * DV + e] =
            f2bf(Y[mi][nt][reg] * invd[reg]);
      }
  }
}

// ---------------------------------------------------------------------------
extern "C" void kernel_launch(void* const* d_in, const int* in_sizes, int n_in,
                              void* d_out, int out_size, void* d_ws, size_t ws_size,
                              hipStream_t stream) {
  const float* hs = (const float*)d_in[0];
  const float* Wq = (const float*)d_in[1];
  const float* Wk = (const float*)d_in[2];
  const float* Wv = (const float*)d_in[3];
  const float* Wo = (const float*)d_in[4];
  float* out = (float*)d_out;

  // workspace layout (~79 MB)
  float* qkb = (float*)d_ws;                                // 4096 x 512 f32 (q|k)
  float* vb  = qkb + (size_t)ROWS * 512;                    // 4096 x 1024 f32
  unsigned short* Sb16 = (unsigned short*)(vb + (size_t)ROWS * (NH * DV)); // 512*273*64 bf16
  float* ub = (float*)(Sb16 + (size_t)NBC * FDIM * DV);     // 512*273 f32
  unsigned short* PG = (unsigned short*)(ub + (size_t)NBC * FDIM); // 512*45*512 bf16
  unsigned short* hsb = PG + (size_t)NBC * 45 * 512;
  unsigned short* yb  = hsb;  // alias: hsb dead after projection GEMMs
  unsigned short* wqt = hsb + (size_t)ROWS * DMODEL;
  unsigned short* wkt = wqt + (size_t)(NH * DQK) * DMODEL;  // adjacent -> [Wq|Wk]^T
  unsigned short* wvt = wkt + (size_t)(NH * DQK) * DMODEL;
  unsigned short* wot = wvt + (size_t)(NH * DV) * DMODEL;

  // casts / transposes
  cast4<<<dim3((ROWS * DMODEL / 4 + 255) / 256), 256, 0, stream>>>(hs, hsb, ROWS * DMODEL / 4);
  transpose_cast<<<dim3((NH * DQK) / 32, DMODEL / 32), 256, 0, stream>>>(Wq, wqt, DMODEL, NH * DQK);
  transpose_cast<<<dim3((NH * DQK) / 32, DMODEL / 32), 256, 0, stream>>>(Wk, wkt, DMODEL, NH * DQK);
  transpose_cast<<<dim3((NH * DV) / 32, DMODEL / 32), 256, 0, stream>>>(Wv, wvt, DMODEL, NH * DV);
  transpose_cast<<<dim3(DMODEL / 32, DMODEL / 32), 256, 0, stream>>>(Wo, wot, DMODEL, DMODEL);

  // projections (MFMA): merged q|k (N=512), v (N=1024)
  gemm_mfma<<<dim3(512 / 128, ROWS / 128), 256, 0, stream>>>(hsb, wqt, qkb, ROWS, 512, DMODEL);
  gemm_mfma<<<dim3((NH * DV) / 128, ROWS / 128), 256, 0, stream>>>(hsb, wvt, vb, ROWS, NH * DV, DMODEL);

  // chunked causal linear attention
  chunk_sums_mfma<<<dim3(NCH, NBH), 256, 0, stream>>>(qkb, vb, Sb16, ub);
  prefix_scan_frag<<<dim3(36, NBH), 128, 0, stream>>>(Sb16, ub, PG);
  attn_mfma<<<dim3(NCH, NBH), 256, 0, stream>>>(qkb, vb, PG, yb);

  // output projection (MFMA)
  gemm_mfma<<<dim3(DMODEL / 128, ROWS / 128), 256, 0, stream>>>(yb, wot, out, ROWS, DMODEL, DMODEL);
}

// Round 8
// 272.346 us; speedup vs baseline: 1.0137x; 1.0137x over previous
//
#include <hip/hip_runtime.h>
#include <hip/hip_bf16.h>

// Problem constants
#define BATCH 2
#define LSEQ 2048
#define DMODEL 1024
#define NH 16
#define DQK 16
#define DV 64
#define FDIM 273            // 1 + 16 + 256
#define CHUNK 128
#define NCH (LSEQ / CHUNK)  // 16 chunks per batch row
#define ROWS (BATCH * LSEQ) // 4096
#define NBH (BATCH * NH)    // 32
#define NBC (NBH * NCH)     // 512 (b,h,chunk) units
#define C2 0.17677669529663687f  // 1/(4*sqrt(2))

typedef short bf16x8 __attribute__((ext_vector_type(8)));
typedef float f32x4 __attribute__((ext_vector_type(4)));

__device__ __forceinline__ unsigned short f2bf(float f) {
  __hip_bfloat16 h = __float2bfloat16(f);
  unsigned short u; __builtin_memcpy(&u, &h, 2); return u;
}
__device__ __forceinline__ float bf2f(unsigned short u) {
  unsigned int v = (unsigned int)u << 16; float f; __builtin_memcpy(&f, &v, 4); return f;
}

// ---------------------------------------------------------------------------
// fp32 -> bf16 elementwise cast (float4 / ushort4 vectorized)
// ---------------------------------------------------------------------------
__global__ __launch_bounds__(256) void cast4(const float* __restrict__ in,
                                             unsigned short* __restrict__ out, int n4) {
  int i = blockIdx.x * 256 + threadIdx.x;
  if (i >= n4) return;
  float4 v = ((const float4*)in)[i];
  ushort4 o = {f2bf(v.x), f2bf(v.y), f2bf(v.z), f2bf(v.w)};
  ((ushort4*)out)[i] = o;
}

// ---------------------------------------------------------------------------
// All four W (KxN fp32) -> Wt (NxK bf16) transposes in ONE launch.
// z selects the matrix; x-blocks beyond N/32 early-exit.
// ---------------------------------------------------------------------------
__global__ __launch_bounds__(256) void transpose_cast_all(
    const float* __restrict__ Wq, const float* __restrict__ Wk,
    const float* __restrict__ Wv, const float* __restrict__ Wo,
    unsigned short* __restrict__ wqt, unsigned short* __restrict__ wkt,
    unsigned short* __restrict__ wvt, unsigned short* __restrict__ wot) {
  __shared__ float t[32][33];
  const float* W; unsigned short* Wt; int N;
  switch (blockIdx.z) {
    case 0: W = Wq; Wt = wqt; N = 256; break;
    case 1: W = Wk; Wt = wkt; N = 256; break;
    case 2: W = Wv; Wt = wvt; N = 1024; break;
    default: W = Wo; Wt = wot; N = 1024; break;
  }
  const int nb = blockIdx.x * 32;
  if (nb >= N) return;
  const int kb = blockIdx.y * 32;
  const int tx = threadIdx.x & 31, ty4 = (threadIdx.x >> 5) * 4;
#pragma unroll
  for (int r = 0; r < 4; r++)
    t[ty4 + r][tx] = W[(size_t)(kb + ty4 + r) * N + nb + tx];
  __syncthreads();
#pragma unroll
  for (int r = 0; r < 4; r++)
    Wt[(size_t)(nb + ty4 + r) * DMODEL + kb + tx] = f2bf(t[tx][ty4 + r]);
}

// ---------------------------------------------------------------------------
// MFMA GEMM (m97 pattern): C(MxN fp32) = A(MxK bf16) @ Bt(NxK bf16)^T.
// 128x128 tile, BK=32, 256 threads = 4 waves, each wave a 64x64 quadrant.
// ---------------------------------------------------------------------------
__global__ __launch_bounds__(256) void gemm_mfma(
    const unsigned short* __restrict__ A, const unsigned short* __restrict__ Bt,
    float* __restrict__ C, int M, int N, int K) {
  __shared__ unsigned short As[512 * 8];
  __shared__ unsigned short Bs[512 * 8];
  const int tid = threadIdx.x;
  const int bm = blockIdx.y * 128, bn = blockIdx.x * 128;
  const int lane = tid & 63;
  const int w = tid >> 6;
  const int qr = (w >> 1) * 64, qc = (w & 1) * 64;
  f32x4 acc[4][4] = {};

  for (int k0 = 0; k0 < K; k0 += 32) {
#pragma unroll
    for (int j = 0; j < 4; ++j) {
      int c = j * 256 + tid;
      int cc = c & 511;
      int row = ((cc >> 6) << 4) + (cc & 15);
      int kh = (cc >> 4) & 3;
      const unsigned short* gp;
      unsigned short* lp;
      if (c < 512) { gp = A  + (size_t)(bm + row) * K + k0 + kh * 8; lp = As + cc * 8; }
      else         { gp = Bt + (size_t)(bn + row) * K + k0 + kh * 8; lp = Bs + cc * 8; }
      __builtin_amdgcn_global_load_lds(
          (const __attribute__((address_space(1))) unsigned int*)(const void*)gp,
          (__attribute__((address_space(3))) unsigned int*)lp, 16, 0, 0);
    }
    __syncthreads();
    bf16x8 a[4], b[4];
#pragma unroll
    for (int i = 0; i < 4; ++i) {
      a[i] = *(const bf16x8*)(As + ((qr >> 4) + i) * 512 + lane * 8);
      b[i] = *(const bf16x8*)(Bs + ((qc >> 4) + i) * 512 + lane * 8);
    }
#pragma unroll
    for (int i = 0; i < 4; ++i)
#pragma unroll
      for (int jj = 0; jj < 4; ++jj)
        acc[i][jj] = __builtin_amdgcn_mfma_f32_16x16x32_bf16(a[i], b[jj], acc[i][jj], 0, 0, 0);
    __syncthreads();
  }
  const int cn = lane & 15, r0 = (lane >> 4) * 4;
#pragma unroll
  for (int i = 0; i < 4; ++i)
#pragma unroll
    for (int jj = 0; jj < 4; ++jj) {
      size_t base = (size_t)(bm + qr + i * 16 + r0) * N + bn + qc + jj * 16 + cn;
#pragma unroll
      for (int r = 0; r < 4; ++r) C[base + (size_t)r * N] = acc[i][jj][r];
    }
}

// ---------------------------------------------------------------------------
// Pass 1 (MFMA): S_c = Kf^T[288x128] @ [V|1|pad][128x80] per (b,h,chunk).
// Kf A-fragments generated on the fly (bf16), double-buffered.  S out in bf16.
// ---------------------------------------------------------------------------
__global__ __launch_bounds__(256) void chunk_sums_mfma(
    const float* __restrict__ qkb, const float* __restrict__ vbuf,
    unsigned short* __restrict__ Sb16, float* __restrict__ ubuf) {
  const int c = blockIdx.x, bh = blockIdx.y;
  const int b = bh >> 4, h = bh & 15;
  const int tid = threadIdx.x;
  const int lane = tid & 63, w = tid >> 6;
  const int row0 = b * LSEQ + c * CHUNK;

  __shared__ float ksT[16 * 132];   // k transposed [d][i], stride 132
  __shared__ short Vp[20 * 512];    // B-operand [V | 1 | 0-pad]
  __shared__ short Kf[2][18 * 512]; // A-operand dbuf (one 32-k slice)

  {
    int i = tid >> 1, d0 = (tid & 1) * 8;
    const float* src = qkb + (size_t)(row0 + i) * 512 + 256 + h * 16 + d0;
    float4 v0 = *(const float4*)src;
    float4 v1 = *(const float4*)(src + 4);
    ksT[(d0 + 0) * 132 + i] = v0.x; ksT[(d0 + 1) * 132 + i] = v0.y;
    ksT[(d0 + 2) * 132 + i] = v0.z; ksT[(d0 + 3) * 132 + i] = v0.w;
    ksT[(d0 + 4) * 132 + i] = v1.x; ksT[(d0 + 5) * 132 + i] = v1.y;
    ksT[(d0 + 6) * 132 + i] = v1.z; ksT[(d0 + 7) * 132 + i] = v1.w;
  }
  for (int t = tid; t < 1280; t += 256) {
    int e, jg;
    if (t < 1024) { e = t & 63; jg = t >> 6; }
    else { int x = t - 1024; e = 64 + (x & 15); jg = x >> 4; }
    bf16x8 v8;
#pragma unroll
    for (int jj = 0; jj < 8; jj++) {
      float val;
      if (e < 64) val = vbuf[(size_t)(row0 + jg * 8 + jj) * (NH * DV) + h * DV + e];
      else val = (e == 64) ? 1.0f : 0.0f;
      v8[jj] = (short)f2bf(val);
    }
    *(bf16x8*)(Vp + ((e >> 4) * 4 + (jg >> 2)) * 512 + ((jg & 3) * 16 + (e & 15)) * 8) = v8;
  }
  __syncthreads();

  auto gen = [&](int kt) {
    for (int o = tid; o < 1152; o += 256) {
      int mt = o >> 6, w6 = o & 63;
      int kh = w6 >> 4, m = w6 & 15;
      int f = mt * 16 + m;
      int i0 = kt * 32 + kh * 8;
      bf16x8 v8;
      if (f == 0) {
#pragma unroll
        for (int j = 0; j < 8; j++) v8[j] = (short)0x3F80;
      } else if (f < 17) {
        const float* ka = &ksT[(f - 1) * 132 + i0];
        float4 a0 = *(const float4*)ka, a1 = *(const float4*)(ka + 4);
        v8[0] = (short)f2bf(0.5f * a0.x); v8[1] = (short)f2bf(0.5f * a0.y);
        v8[2] = (short)f2bf(0.5f * a0.z); v8[3] = (short)f2bf(0.5f * a0.w);
        v8[4] = (short)f2bf(0.5f * a1.x); v8[5] = (short)f2bf(0.5f * a1.y);
        v8[6] = (short)f2bf(0.5f * a1.z); v8[7] = (short)f2bf(0.5f * a1.w);
      } else if (f < FDIM) {
        int ix = f - 17;
        const float* ka = &ksT[(ix >> 4) * 132 + i0];
        const float* kb2 = &ksT[(ix & 15) * 132 + i0];
        float4 a0 = *(const float4*)ka, a1 = *(const float4*)(ka + 4);
        float4 b0 = *(const float4*)kb2, b1 = *(const float4*)(kb2 + 4);
        v8[0] = (short)f2bf(C2 * a0.x * b0.x); v8[1] = (short)f2bf(C2 * a0.y * b0.y);
        v8[2] = (short)f2bf(C2 * a0.z * b0.z); v8[3] = (short)f2bf(C2 * a0.w * b0.w);
        v8[4] = (short)f2bf(C2 * a1.x * b1.x); v8[5] = (short)f2bf(C2 * a1.y * b1.y);
        v8[6] = (short)f2bf(C2 * a1.z * b1.z); v8[7] = (short)f2bf(C2 * a1.w * b1.w);
      } else {
#pragma unroll
        for (int j = 0; j < 8; j++) v8[j] = 0;
      }
      *(bf16x8*)(Kf[kt & 1] + mt * 512 + (kh * 16 + m) * 8) = v8;
    }
  };

  gen(0);
  __syncthreads();

  f32x4 acc[5][5] = {};
  const int nmt = (w < 2) ? 5 : 4;
  for (int kt = 0; kt < 4; kt++) {
    if (kt < 3) gen(kt + 1);
    bf16x8 bv[5];
#pragma unroll
    for (int nt = 0; nt < 5; nt++)
      bv[nt] = *(const bf16x8*)(Vp + (nt * 4 + kt) * 512 + lane * 8);
#pragma unroll
    for (int t2 = 0; t2 < 5; t2++) {
      if (t2 < nmt) {  // wave-uniform; keeps acc indices compile-time (R5 lesson)
        int mt = w + t2 * 4;
        bf16x8 av = *(const bf16x8*)(Kf[kt & 1] + mt * 512 + lane * 8);
#pragma unroll
        for (int nt = 0; nt < 5; nt++)
          acc[t2][nt] = __builtin_amdgcn_mfma_f32_16x16x32_bf16(av, bv[nt], acc[t2][nt], 0, 0, 0);
      }
    }
    __syncthreads();
  }

  const int cl = lane & 15, r0q = (lane >> 4) * 4;
  const size_t sbase = ((size_t)bh * NCH + c) * FDIM;
#pragma unroll
  for (int t2 = 0; t2 < 5; t2++) {
    if (t2 < nmt) {
      int mt = w + t2 * 4;
#pragma unroll
      for (int reg = 0; reg < 4; reg++) {
        int f = mt * 16 + r0q + reg;
        if (f < FDIM) {
#pragma unroll
          for (int nt = 0; nt < 4; nt++)
            Sb16[(sbase + f) * DV + nt * 16 + cl] = f2bf(acc[t2][nt][reg]);
          if (cl == 0) ubuf[sbase + f] = acc[t2][4][reg];
        }
      }
    }
  }
}

// ---------------------------------------------------------------------------
// Pass 2: exclusive prefix over chunks, emitted DIRECTLY in bf16 MFMA
// B-fragment layout: PG[((bh*16+c)*45 + kt*5 + nt)*512 + (kh*16 + n)*8 + (f&7)]
// covering [P | u | 0-pad] (N=80, K=288).  attn reads fragments straight from
// global (lane*16B coalesced), so no LDS staging is needed there.
// ---------------------------------------------------------------------------
__global__ __launch_bounds__(128) void prefix_scan_frag(
    const unsigned short* __restrict__ Sb16, const float* __restrict__ ubuf,
    unsigned short* __restrict__ PG) {
  const int g = blockIdx.x, bh = blockIdx.y;
  const int e = threadIdx.x;
  if (e >= 80) return;
  const int f0 = g * 8;
  const int kt = f0 >> 5, kh = (f0 >> 3) & 3;
  const int nt = e >> 4, n = e & 15;
  float run[8] = {0.f, 0.f, 0.f, 0.f, 0.f, 0.f, 0.f, 0.f};
#pragma unroll
  for (int cc = 0; cc < NCH; cc++) {
    bf16x8 v8;
#pragma unroll
    for (int j = 0; j < 8; j++) v8[j] = (short)f2bf(run[j]);
    *(bf16x8*)(PG + ((size_t)(bh * NCH + cc) * 45 + kt * 5 + nt) * 512 +
               (kh * 16 + n) * 8) = v8;
    const size_t sb = ((size_t)bh * NCH + cc) * FDIM;
    if (e < 64) {
#pragma unroll
      for (int j = 0; j < 8; j++) {
        int f = f0 + j;
        if (f < FDIM) run[j] += bf2f(Sb16[(sb + f) * DV + e]);
      }
    } else if (e == 64) {
#pragma unroll
      for (int j = 0; j < 8; j++) {
        int f = f0 + j;
        if (f < FDIM) run[j] += ubuf[sb + f];
      }
    }
  }
}

// ---------------------------------------------------------------------------
// Pass 3 (MFMA): per-(b,h,chunk) outputs -> bf16 y.
// LDS union U (78 KB, 2 blocks/CU):
//   phase 1: Qb U[0..4095], Kb U[4096..8191]; epi-> Am U[8192..24575]
//   phase 2: Vp U[24576..34815]; qsB (bf16 q, stride 17) U[36864..39039]
//   Qf gen : full 128x288 Qf A-fragments -> U[0..36863] (once)
//   phase 3: barrier-FREE: B-fragments loaded straight from PG (lane*16B),
//            A-fragments from the read-only Qf region.
// ---------------------------------------------------------------------------
__global__ __launch_bounds__(256) void attn_mfma(
    const float* __restrict__ qkb, const float* __restrict__ vbuf,
    const unsigned short* __restrict__ PG, unsigned short* __restrict__ ybuf) {
  const int c = blockIdx.x, bh = blockIdx.y;
  const int b = bh >> 4, h = bh & 15;
  const int tid = threadIdx.x;
  const int lane = tid & 63, w = tid >> 6;
  const int row0 = b * LSEQ + c * CHUNK;

  __shared__ short U[39040];
  __shared__ float denL[128];
  unsigned short* Uu = (unsigned short*)U;

  // ---- stage qsB (bf16 q rows, stride 17 -> conflict-free gathers) ----
  {
    int i = tid >> 1, d0 = (tid & 1) * 8;
    const float* src = qkb + (size_t)(row0 + i) * 512 + h * 16 + d0;
    float4 v0 = *(const float4*)src;
    float4 v1 = *(const float4*)(src + 4);
    unsigned short* qd = Uu + 36864 + i * 17 + d0;
    qd[0] = f2bf(v0.x); qd[1] = f2bf(v0.y); qd[2] = f2bf(v0.z); qd[3] = f2bf(v0.w);
    qd[4] = f2bf(v1.x); qd[5] = f2bf(v1.y); qd[6] = f2bf(v1.z); qd[7] = f2bf(v1.w);
  }
  // ---- stage Qb, Kb (bf16 fragments, K padded to 32 with zeros) ----
  for (int t = tid; t < 1024; t += 256) {
    int isK = t >> 9;
    int tt = t & 511;
    int i = tt >> 2, kh = tt & 3;
    bf16x8 v8 = {0, 0, 0, 0, 0, 0, 0, 0};
    if (kh < 2) {
      const float* src = qkb + (size_t)(row0 + i) * 512 + isK * 256 + h * 16 + kh * 8;
      float4 a = *(const float4*)src;
      float4 bq = *(const float4*)(src + 4);
      v8[0] = (short)f2bf(a.x);  v8[1] = (short)f2bf(a.y);
      v8[2] = (short)f2bf(a.z);  v8[3] = (short)f2bf(a.w);
      v8[4] = (short)f2bf(bq.x); v8[5] = (short)f2bf(bq.y);
      v8[6] = (short)f2bf(bq.z); v8[7] = (short)f2bf(bq.w);
    }
    *(bf16x8*)(U + isK * 4096 + (i >> 4) * 512 + (kh * 16 + (i & 15)) * 8) = v8;
  }
  __syncthreads();

  // ---- phase 1: S = Q K^T -> poly+mask -> Am (A-fragment layout) ----
  {
    bf16x8 aq[2];
#pragma unroll
    for (int mi = 0; mi < 2; mi++)
      aq[mi] = *(const bf16x8*)(U + (w * 2 + mi) * 512 + lane * 8);
    f32x4 S[2][8] = {};
#pragma unroll
    for (int nt = 0; nt < 8; nt++) {
      bf16x8 bk = *(const bf16x8*)(U + 4096 + nt * 512 + lane * 8);
#pragma unroll
      for (int mi = 0; mi < 2; mi++)
        S[mi][nt] = __builtin_amdgcn_mfma_f32_16x16x32_bf16(aq[mi], bk, S[mi][nt], 0, 0, 0);
    }
    __syncthreads();  // Qb/Kb reads done before Am overwrites U[8192..]
    const int cl = lane & 15, r0q = (lane >> 4) * 4;
#pragma unroll
    for (int mi = 0; mi < 2; mi++)
#pragma unroll
      for (int nt = 0; nt < 8; nt++)
#pragma unroll
        for (int reg = 0; reg < 4; reg++) {
          int i = (w * 2 + mi) * 16 + r0q + reg;
          int j = nt * 16 + cl;
          float s = S[mi][nt][reg];
          float aij = (j <= i) ? fmaf(s, fmaf(s, 0.03125f, 0.25f), 1.0f) : 0.0f;
          U[8192 + ((i >> 4) * 4 + (j >> 5)) * 512 +
            (((j >> 3) & 3) * 16 + (i & 15)) * 8 + (j & 7)] = (short)f2bf(aij);
        }
  }
  // ---- stage Vp = [V | 1 | 0-pad] (B-operand, N=80, K=128) ----
  for (int t = tid; t < 1280; t += 256) {
    int e, jg;
    if (t < 1024) { e = t & 63; jg = t >> 6; }
    else { int x = t - 1024; e = 64 + (x & 15); jg = x >> 4; }
    bf16x8 v8;
#pragma unroll
    for (int jj = 0; jj < 8; jj++) {
      float val;
      if (e < 64) val = vbuf[(size_t)(row0 + jg * 8 + jj) * (NH * DV) + h * DV + e];
      else val = (e == 64) ? 1.0f : 0.0f;
      v8[jj] = (short)f2bf(val);
    }
    *(bf16x8*)(U + 24576 + ((e >> 4) * 4 + (jg >> 2)) * 512 +
               ((jg & 3) * 16 + (e & 15)) * 8) = v8;
  }
  __syncthreads();

  // ---- phase 2: Y = A · Vp ----
  f32x4 Y[2][5] = {};
#pragma unroll
  for (int kc = 0; kc < 4; kc++) {
    bf16x8 a2[2];
#pragma unroll
    for (int mi = 0; mi < 2; mi++)
      a2[mi] = *(const bf16x8*)(U + 8192 + ((w * 2 + mi) * 4 + kc) * 512 + lane * 8);
#pragma unroll
    for (int nt = 0; nt < 5; nt++) {
      bf16x8 b2 = *(const bf16x8*)(U + 24576 + (nt * 4 + kc) * 512 + lane * 8);
#pragma unroll
      for (int mi = 0; mi < 2; mi++)
        Y[mi][nt] = __builtin_amdgcn_mfma_f32_16x16x32_bf16(a2[mi], b2, Y[mi][nt], 0, 0, 0);
    }
  }
  __syncthreads();  // phase-2 reads done; U[0..36863] free for Qf

  // ---- Qf gen: full 128x288 A-fragments into U[0..36863] (once) ----
#pragma unroll 2
  for (int iter = 0; iter < 18; iter++) {
    int gv = iter * 256 + tid;
    int kt = gv >> 9;
    int w9 = gv & 511;
    int row = ((w9 >> 6) << 4) + (w9 & 15);
    int kh = (w9 >> 4) & 3;
    const unsigned short* qr = Uu + 36864 + row * 17;
    bf16x8 v8;
#pragma unroll
    for (int j = 0; j < 8; j++) {
      int f = kt * 32 + kh * 8 + j;
      float qf;
      if (f == 0) qf = 1.0f;
      else if (f < 17) qf = 0.5f * bf2f(qr[f - 1]);
      else if (f < FDIM) {
        int ix = f - 17;
        qf = C2 * bf2f(qr[ix >> 4]) * bf2f(qr[ix & 15]);
      } else qf = 0.0f;
      v8[j] = (short)f2bf(qf);
    }
    *(bf16x8*)(U + (size_t)gv * 8) = v8;
  }
  __syncthreads();  // Qf complete; phase 3 is barrier-free from here

  // ---- phase 3: Y += Qf · [P|u]; B-fragments DIRECT from global PG ----
  const unsigned short* pgl = PG + ((size_t)bh * NCH + c) * 45 * 512 + lane * 8;
#pragma unroll
  for (int ft = 0; ft < 9; ft++) {
    bf16x8 b3[5];
#pragma unroll
    for (int nt = 0; nt < 5; nt++)
      b3[nt] = *(const bf16x8*)(pgl + (ft * 5 + nt) * 512);
    bf16x8 a3[2];
#pragma unroll
    for (int mi = 0; mi < 2; mi++)
      a3[mi] = *(const bf16x8*)(U + ft * 4096 + (w * 2 + mi) * 512 + lane * 8);
#pragma unroll
    for (int nt = 0; nt < 5; nt++)
#pragma unroll
      for (int mi = 0; mi < 2; mi++)
        Y[mi][nt] = __builtin_amdgcn_mfma_f32_16x16x32_bf16(a3[mi], b3[nt], Y[mi][nt], 0, 0, 0);
  }

  // ---- epilogue: den from ones column (nt=4, col 0), scale, store bf16 ----
  const int cl = lane & 15, r0q = (lane >> 4) * 4;
  if (cl == 0) {
#pragma unroll
    for (int mi = 0; mi < 2; mi++)
#pragma unroll
      for (int reg = 0; reg < 4; reg++)
        denL[(w * 2 + mi) * 16 + r0q + reg] = Y[mi][4][reg];
  }
  __syncthreads();
#pragma unroll
  for (int mi = 0; mi < 2; mi++) {
    float invd[4];
#pragma unroll
    for (int reg = 0; reg < 4; reg++)
      invd[reg] = 1.0f / (denL[(w * 2 + mi) * 16 + r0q + reg] + 1e-12f);
#pragma unroll
    for (int nt = 0; nt < 4; nt++)
#pragma unroll
      for (int reg = 0; reg < 4; reg++) {
        int i = (w * 2 + mi) * 16 + r0q + reg;
        int e = nt * 16 + cl;
        ybuf[(size_t)(row0 + i) * (NH * DV) + h * DV + e] =
            f2bf(Y[mi][nt][reg] * invd[reg]);
      }
  }
}

// ---------------------------------------------------------------------------
extern "C" void kernel_launch(void* const* d_in, const int* in_sizes, int n_in,
                              void* d_out, int out_size, void* d_ws, size_t ws_size,
                              hipStream_t stream) {
  const float* hs = (const float*)d_in[0];
  const float* Wq = (const float*)d_in[1];
  const float* Wk = (const float*)d_in[2];
  const float* Wv = (const float*)d_in[3];
  const float* Wo = (const float*)d_in[4];
  float* out = (float*)d_out;

  // workspace layout (~79 MB)
  float* qkb = (float*)d_ws;                                // 4096 x 512 f32 (q|k)
  float* vb  = qkb + (size_t)ROWS * 512;                    // 4096 x 1024 f32
  unsigned short* Sb16 = (unsigned short*)(vb + (size_t)ROWS * (NH * DV)); // 512*273*64 bf16
  float* ub = (float*)(Sb16 + (size_t)NBC * FDIM * DV);     // 512*273 f32
  unsigned short* PG = (unsigned short*)(ub + (size_t)NBC * FDIM); // 512*45*512 bf16
  unsigned short* hsb = PG + (size_t)NBC * 45 * 512;
  unsigned short* yb  = hsb;  // alias: hsb dead after projection GEMMs
  unsigned short* wqt = hsb + (size_t)ROWS * DMODEL;
  unsigned short* wkt = wqt + (size_t)(NH * DQK) * DMODEL;  // adjacent -> [Wq|Wk]^T
  unsigned short* wvt = wkt + (size_t)(NH * DQK) * DMODEL;
  unsigned short* wot = wvt + (size_t)(NH * DV) * DMODEL;

  // casts / transposes
  cast4<<<dim3((ROWS * DMODEL / 4 + 255) / 256), 256, 0, stream>>>(hs, hsb, ROWS * DMODEL / 4);
  transpose_cast_all<<<dim3(32, 32, 4), 256, 0, stream>>>(Wq, Wk, Wv, Wo, wqt, wkt, wvt, wot);

  // projections (MFMA): merged q|k (N=512), v (N=1024)
  gemm_mfma<<<dim3(512 / 128, ROWS / 128), 256, 0, stream>>>(hsb, wqt, qkb, ROWS, 512, DMODEL);
  gemm_mfma<<<dim3((NH * DV) / 128, ROWS / 128), 256, 0, stream>>>(hsb, wvt, vb, ROWS, NH * DV, DMODEL);

  // chunked causal linear attention
  chunk_sums_mfma<<<dim3(NCH, NBH), 256, 0, stream>>>(qkb, vb, Sb16, ub);
  prefix_scan_frag<<<dim3(36, NBH), 128, 0, stream>>>(Sb16, ub, PG);
  attn_mfma<<<dim3(NCH, NBH), 256, 0, stream>>>(qkb, vb, PG, yb);

  // output projection (MFMA)
  gemm_mfma<<<dim3(DMODEL / 128, ROWS / 128), 256, 0, stream>>>(yb, wot, out, ROWS, DMODEL, DMODEL);
}

// Round 9
// 205.202 us; speedup vs baseline: 1.3454x; 1.3272x over previous
//
#include <hip/hip_runtime.h>
#include <hip/hip_bf16.h>

// Problem constants
#define BATCH 2
#define LSEQ 2048
#define DMODEL 1024
#define NH 16
#define DQK 16
#define DV 64
#define FDIM 273            // 1 + 16 + 256
#define CHUNK 128
#define NCH (LSEQ / CHUNK)  // 16 chunks per batch row
#define ROWS (BATCH * LSEQ) // 4096
#define NBH (BATCH * NH)    // 32
#define NBC (NBH * NCH)     // 512 (b,h,chunk) units
#define QKVW 1536           // fused qkv row stride (bf16)
#define C2 0.17677669529663687f  // 1/(4*sqrt(2))

typedef short bf16x8 __attribute__((ext_vector_type(8)));
typedef float f32x4 __attribute__((ext_vector_type(4)));

__device__ __forceinline__ unsigned short f2bf(float f) {
  __hip_bfloat16 h = __float2bfloat16(f);
  unsigned short u; __builtin_memcpy(&u, &h, 2); return u;
}
__device__ __forceinline__ float bf2f(unsigned short u) {
  unsigned int v = (unsigned int)u << 16; float f; __builtin_memcpy(&f, &v, 4); return f;
}

__device__ __forceinline__ void storeC(float* C, size_t off, float v) { C[off] = v; }
__device__ __forceinline__ void storeC(unsigned short* C, size_t off, float v) {
  C[off] = f2bf(v);
}

// ---------------------------------------------------------------------------
// fp32 -> bf16 elementwise cast (float4 / ushort4 vectorized)
// ---------------------------------------------------------------------------
__global__ __launch_bounds__(256) void cast4(const float* __restrict__ in,
                                             unsigned short* __restrict__ out, int n4) {
  int i = blockIdx.x * 256 + threadIdx.x;
  if (i >= n4) return;
  float4 v = ((const float4*)in)[i];
  ushort4 o = {f2bf(v.x), f2bf(v.y), f2bf(v.z), f2bf(v.w)};
  ((ushort4*)out)[i] = o;
}

// ---------------------------------------------------------------------------
// All four W (KxN fp32) -> Wt (NxK bf16) transposes in ONE launch.
// wqt/wkt/wvt land contiguously -> combined 1536x1024 QKV weight.
// ---------------------------------------------------------------------------
__global__ __launch_bounds__(256) void transpose_cast_all(
    const float* __restrict__ Wq, const float* __restrict__ Wk,
    const float* __restrict__ Wv, const float* __restrict__ Wo,
    unsigned short* __restrict__ wqt, unsigned short* __restrict__ wkt,
    unsigned short* __restrict__ wvt, unsigned short* __restrict__ wot) {
  __shared__ float t[32][33];
  const float* W; unsigned short* Wt; int N;
  switch (blockIdx.z) {
    case 0: W = Wq; Wt = wqt; N = 256; break;
    case 1: W = Wk; Wt = wkt; N = 256; break;
    case 2: W = Wv; Wt = wvt; N = 1024; break;
    default: W = Wo; Wt = wot; N = 1024; break;
  }
  const int nb = blockIdx.x * 32;
  if (nb >= N) return;
  const int kb = blockIdx.y * 32;
  const int tx = threadIdx.x & 31, ty4 = (threadIdx.x >> 5) * 4;
#pragma unroll
  for (int r = 0; r < 4; r++)
    t[ty4 + r][tx] = W[(size_t)(kb + ty4 + r) * N + nb + tx];
  __syncthreads();
#pragma unroll
  for (int r = 0; r < 4; r++)
    Wt[(size_t)(nb + ty4 + r) * DMODEL + kb + tx] = f2bf(t[tx][ty4 + r]);
}

// ---------------------------------------------------------------------------
// MFMA GEMM (m97 pattern): C(MxN) = A(MxK bf16) @ Bt(NxK bf16)^T, C fp32/bf16.
// 128x128 tile, BK=32, 256 threads = 4 waves, each wave a 64x64 quadrant.
// ---------------------------------------------------------------------------
template <typename CT>
__global__ __launch_bounds__(256) void gemm_mfma(
    const unsigned short* __restrict__ A, const unsigned short* __restrict__ Bt,
    CT* __restrict__ C, int M, int N, int K) {
  __shared__ unsigned short As[512 * 8];
  __shared__ unsigned short Bs[512 * 8];
  const int tid = threadIdx.x;
  const int bm = blockIdx.y * 128, bn = blockIdx.x * 128;
  const int lane = tid & 63;
  const int w = tid >> 6;
  const int qr = (w >> 1) * 64, qc = (w & 1) * 64;
  f32x4 acc[4][4] = {};

  for (int k0 = 0; k0 < K; k0 += 32) {
#pragma unroll
    for (int j = 0; j < 4; ++j) {
      int c = j * 256 + tid;
      int cc = c & 511;
      int row = ((cc >> 6) << 4) + (cc & 15);
      int kh = (cc >> 4) & 3;
      const unsigned short* gp;
      unsigned short* lp;
      if (c < 512) { gp = A  + (size_t)(bm + row) * K + k0 + kh * 8; lp = As + cc * 8; }
      else         { gp = Bt + (size_t)(bn + row) * K + k0 + kh * 8; lp = Bs + cc * 8; }
      __builtin_amdgcn_global_load_lds(
          (const __attribute__((address_space(1))) unsigned int*)(const void*)gp,
          (__attribute__((address_space(3))) unsigned int*)lp, 16, 0, 0);
    }
    __syncthreads();
    bf16x8 a[4], b[4];
#pragma unroll
    for (int i = 0; i < 4; ++i) {
      a[i] = *(const bf16x8*)(As + ((qr >> 4) + i) * 512 + lane * 8);
      b[i] = *(const bf16x8*)(Bs + ((qc >> 4) + i) * 512 + lane * 8);
    }
#pragma unroll
    for (int i = 0; i < 4; ++i)
#pragma unroll
      for (int jj = 0; jj < 4; ++jj)
        acc[i][jj] = __builtin_amdgcn_mfma_f32_16x16x32_bf16(a[i], b[jj], acc[i][jj], 0, 0, 0);
    __syncthreads();
  }
  const int cn = lane & 15, r0 = (lane >> 4) * 4;
#pragma unroll
  for (int i = 0; i < 4; ++i)
#pragma unroll
    for (int jj = 0; jj < 4; ++jj) {
      size_t base = (size_t)(bm + qr + i * 16 + r0) * N + bn + qc + jj * 16 + cn;
#pragma unroll
      for (int r = 0; r < 4; ++r) storeC(C, base + (size_t)r * N, acc[i][jj][r]);
    }
}

// ---------------------------------------------------------------------------
// Pass 1 (MFMA): [S_c|u_c] = Kf^T[288x128] @ [V|1|pad][128x80] per (b,h,chunk),
// emitted DIRECTLY in the PG bf16 B-fragment layout (45 tiles x 512):
//   Sfrag[(kt*5+nt)*512 + (kh*16+n)*8 + j]  with f=kt*32+kh*8+j, e=nt*16+n.
// u = e:64 ones column; all pad slots are naturally 0 (Kf/Vp pads are 0).
// Epilogue goes through an LDS transpose so global stores are bf16x8.
// ---------------------------------------------------------------------------
__global__ __launch_bounds__(256) void chunk_sums_mfma(
    const unsigned short* __restrict__ qkvb, unsigned short* __restrict__ Sfrag) {
  const int c = blockIdx.x, bh = blockIdx.y;
  const int b = bh >> 4, h = bh & 15;
  const int tid = threadIdx.x;
  const int lane = tid & 63, w = tid >> 6;
  const int row0 = b * LSEQ + c * CHUNK;

  __shared__ float ksT[16 * 132];   // k transposed [d][i], stride 132
  __shared__ short SH[56 * 512];    // Vp[0..20*512) | Kf0 | Kf1 ; epi: Sfrag stage
  short* Vp = SH;
  short* Kf0 = SH + 20 * 512;
  short* Kf1 = SH + 38 * 512;

  // ---- stage ksT (fp32 from bf16 k; stride 132 -> 2-way-free banks) ----
  {
    int i = tid >> 1, d0 = (tid & 1) * 8;
    bf16x8 k8 = *(const bf16x8*)(qkvb + (size_t)(row0 + i) * QKVW + 256 + h * 16 + d0);
#pragma unroll
    for (int j = 0; j < 8; j++) ksT[(d0 + j) * 132 + i] = bf2f((unsigned short)k8[j]);
  }
  // ---- stage Vp = [V | 1 | 0-pad] (B-operand, N=80, K=128), bf16 copies ----
  for (int t = tid; t < 1280; t += 256) {
    int e, jg;
    if (t < 1024) { e = t & 63; jg = t >> 6; }
    else { int x = t - 1024; e = 64 + (x & 15); jg = x >> 4; }
    bf16x8 v8;
#pragma unroll
    for (int jj = 0; jj < 8; jj++) {
      short val;
      if (e < 64) val = (short)qkvb[(size_t)(row0 + jg * 8 + jj) * QKVW + 512 + h * 64 + e];
      else val = (e == 64) ? (short)0x3F80 : (short)0;
      v8[jj] = val;
    }
    *(bf16x8*)(Vp + ((e >> 4) * 4 + (jg >> 2)) * 512 + ((jg & 3) * 16 + (e & 15)) * 8) = v8;
  }
  __syncthreads();

  // ---- kf-slice generator: rows i0..i0+31 of Kf^T into Kf buf ----
  auto gen = [&](int kt, short* dst) {
    for (int o = tid; o < 1152; o += 256) {
      int mt = o >> 6, w6 = o & 63;
      int kh = w6 >> 4, m = w6 & 15;
      int f = mt * 16 + m;
      int i0 = kt * 32 + kh * 8;
      bf16x8 v8;
      if (f == 0) {
#pragma unroll
        for (int j = 0; j < 8; j++) v8[j] = (short)0x3F80;
      } else if (f < 17) {
        const float* ka = &ksT[(f - 1) * 132 + i0];
        float4 a0 = *(const float4*)ka, a1 = *(const float4*)(ka + 4);
        v8[0] = (short)f2bf(0.5f * a0.x); v8[1] = (short)f2bf(0.5f * a0.y);
        v8[2] = (short)f2bf(0.5f * a0.z); v8[3] = (short)f2bf(0.5f * a0.w);
        v8[4] = (short)f2bf(0.5f * a1.x); v8[5] = (short)f2bf(0.5f * a1.y);
        v8[6] = (short)f2bf(0.5f * a1.z); v8[7] = (short)f2bf(0.5f * a1.w);
      } else if (f < FDIM) {
        int ix = f - 17;
        const float* ka = &ksT[(ix >> 4) * 132 + i0];
        const float* kb2 = &ksT[(ix & 15) * 132 + i0];
        float4 a0 = *(const float4*)ka, a1 = *(const float4*)(ka + 4);
        float4 b0 = *(const float4*)kb2, b1 = *(const float4*)(kb2 + 4);
        v8[0] = (short)f2bf(C2 * a0.x * b0.x); v8[1] = (short)f2bf(C2 * a0.y * b0.y);
        v8[2] = (short)f2bf(C2 * a0.z * b0.z); v8[3] = (short)f2bf(C2 * a0.w * b0.w);
        v8[4] = (short)f2bf(C2 * a1.x * b1.x); v8[5] = (short)f2bf(C2 * a1.y * b1.y);
        v8[6] = (short)f2bf(C2 * a1.z * b1.z); v8[7] = (short)f2bf(C2 * a1.w * b1.w);
      } else {
#pragma unroll
        for (int j = 0; j < 8; j++) v8[j] = 0;
      }
      *(bf16x8*)(dst + mt * 512 + (kh * 16 + m) * 8) = v8;
    }
  };

  gen(0, Kf0);
  __syncthreads();

  f32x4 acc[5][5] = {};
  const int nmt = (w < 2) ? 5 : 4;
  for (int kt = 0; kt < 4; kt++) {
    short* cur = (kt & 1) ? Kf1 : Kf0;
    if (kt < 3) gen(kt + 1, (kt & 1) ? Kf0 : Kf1);
    bf16x8 bv[5];
#pragma unroll
    for (int nt = 0; nt < 5; nt++)
      bv[nt] = *(const bf16x8*)(Vp + (nt * 4 + kt) * 512 + lane * 8);
#pragma unroll
    for (int t2 = 0; t2 < 5; t2++) {
      if (t2 < nmt) {  // wave-uniform; keeps acc indices compile-time (R5 lesson)
        int mt = w + t2 * 4;
        bf16x8 av = *(const bf16x8*)(cur + mt * 512 + lane * 8);
#pragma unroll
        for (int nt = 0; nt < 5; nt++)
          acc[t2][nt] = __builtin_amdgcn_mfma_f32_16x16x32_bf16(av, bv[nt], acc[t2][nt], 0, 0, 0);
      }
    }
    __syncthreads();
  }

  // ---- epilogue: scatter acc -> SH in fragment layout, then bulk store ----
  const int cl = lane & 15, r0q = (lane >> 4) * 4;
#pragma unroll
  for (int t2 = 0; t2 < 5; t2++) {
    if (t2 < nmt) {
      int mt = w + t2 * 4;
#pragma unroll
      for (int reg = 0; reg < 4; reg++) {
        int f = mt * 16 + r0q + reg;  // 0..287; f>=FDIM values are exact 0
#pragma unroll
        for (int nt = 0; nt < 5; nt++) {
          int e = nt * 16 + cl;       // 0..79; e>64 values are exact 0
          SH[((f >> 5) * 5 + nt) * 512 + (((f >> 3) & 3) * 16 + (e & 15)) * 8 + (f & 7)] =
              (short)f2bf(acc[t2][nt][reg]);
        }
      }
    }
  }
  __syncthreads();
  unsigned short* dst = Sfrag + ((size_t)bh * NCH + c) * 45 * 512;
  for (int o = tid; o < 2880; o += 256)
    *(bf16x8*)(dst + o * 8) = *(const bf16x8*)(SH + o * 8);
}

// ---------------------------------------------------------------------------
// Pass 2: exclusive prefix over chunks in fragment layout, fully vectorized:
// one bf16x8 load + one bf16x8 store per chunk per thread.
// grid (45 tiles, 32 bh) x 64 lanes.
// ---------------------------------------------------------------------------
__global__ __launch_bounds__(64) void prefix_scan_frag(
    const unsigned short* __restrict__ Sfrag, unsigned short* __restrict__ PG) {
  const int kt5 = blockIdx.x, bh = blockIdx.y;
  const int lane = threadIdx.x;
  float run[8] = {0.f, 0.f, 0.f, 0.f, 0.f, 0.f, 0.f, 0.f};
  const size_t base = ((size_t)bh * NCH * 45 + kt5) * 512 + lane * 8;
#pragma unroll
  for (int cc = 0; cc < NCH; cc++) {
    size_t a = base + (size_t)cc * 45 * 512;
    bf16x8 s8 = *(const bf16x8*)(Sfrag + a);
    bf16x8 o8;
#pragma unroll
    for (int j = 0; j < 8; j++) {
      o8[j] = (short)f2bf(run[j]);
      run[j] += bf2f((unsigned short)s8[j]);
    }
    *(bf16x8*)(PG + a) = o8;
  }
}

// ---------------------------------------------------------------------------
// Pass 3 (MFMA): per-(b,h,chunk) outputs -> bf16 y.  (qkv now bf16.)
// LDS union U (78 KB, 2 blocks/CU):
//   phase 1: Qb U[0..4095], Kb U[4096..8191]; epi-> Am U[8192..24575]
//   phase 2: Vp U[24576..34815]; qsB (bf16 q, stride 17) U[36864..39039]
//   Qf gen : full 128x288 Qf A-fragments -> U[0..36863] (once)
//   phase 3: barrier-free; B-fragments loaded straight from PG (lane*16B).
// ---------------------------------------------------------------------------
__global__ __launch_bounds__(256) void attn_mfma(
    const unsigned short* __restrict__ qkvb, const unsigned short* __restrict__ PG,
    unsigned short* __restrict__ ybuf) {
  const int c = blockIdx.x, bh = blockIdx.y;
  const int b = bh >> 4, h = bh & 15;
  const int tid = threadIdx.x;
  const int lane = tid & 63, w = tid >> 6;
  const int row0 = b * LSEQ + c * CHUNK;

  __shared__ short U[39040];
  __shared__ float denL[128];
  unsigned short* Uu = (unsigned short*)U;

  // ---- stage qsB (bf16 q rows, stride 17 -> conflict-free gathers) ----
  {
    int i = tid >> 1, d0 = (tid & 1) * 8;
    bf16x8 q8 = *(const bf16x8*)(qkvb + (size_t)(row0 + i) * QKVW + h * 16 + d0);
    unsigned short* qd = Uu + 36864 + i * 17 + d0;
#pragma unroll
    for (int j = 0; j < 8; j++) qd[j] = (unsigned short)q8[j];
  }
  // ---- stage Qb, Kb (bf16 fragments, K padded to 32 with zeros) ----
  for (int t = tid; t < 1024; t += 256) {
    int isK = t >> 9;
    int tt = t & 511;
    int i = tt >> 2, kh = tt & 3;
    bf16x8 v8 = {0, 0, 0, 0, 0, 0, 0, 0};
    if (kh < 2)
      v8 = *(const bf16x8*)(qkvb + (size_t)(row0 + i) * QKVW + isK * 256 + h * 16 + kh * 8);
    *(bf16x8*)(U + isK * 4096 + (i >> 4) * 512 + (kh * 16 + (i & 15)) * 8) = v8;
  }
  __syncthreads();

  // ---- phase 1: S = Q K^T -> poly+mask -> Am (A-fragment layout) ----
  {
    bf16x8 aq[2];
#pragma unroll
    for (int mi = 0; mi < 2; mi++)
      aq[mi] = *(const bf16x8*)(U + (w * 2 + mi) * 512 + lane * 8);
    f32x4 S[2][8] = {};
#pragma unroll
    for (int nt = 0; nt < 8; nt++) {
      bf16x8 bk = *(const bf16x8*)(U + 4096 + nt * 512 + lane * 8);
#pragma unroll
      for (int mi = 0; mi < 2; mi++)
        S[mi][nt] = __builtin_amdgcn_mfma_f32_16x16x32_bf16(aq[mi], bk, S[mi][nt], 0, 0, 0);
    }
    __syncthreads();  // Qb/Kb reads done before Am overwrites U[8192..]
    const int cl = lane & 15, r0q = (lane >> 4) * 4;
#pragma unroll
    for (int mi = 0; mi < 2; mi++)
#pragma unroll
      for (int nt = 0; nt < 8; nt++)
#pragma unroll
        for (int reg = 0; reg < 4; reg++) {
          int i = (w * 2 + mi) * 16 + r0q + reg;
          int j = nt * 16 + cl;
          float s = S[mi][nt][reg];
          float aij = (j <= i) ? fmaf(s, fmaf(s, 0.03125f, 0.25f), 1.0f) : 0.0f;
          U[8192 + ((i >> 4) * 4 + (j >> 5)) * 512 +
            (((j >> 3) & 3) * 16 + (i & 15)) * 8 + (j & 7)] = (short)f2bf(aij);
        }
  }
  // ---- stage Vp = [V | 1 | 0-pad] (B-operand, N=80, K=128) ----
  for (int t = tid; t < 1280; t += 256) {
    int e, jg;
    if (t < 1024) { e = t & 63; jg = t >> 6; }
    else { int x = t - 1024; e = 64 + (x & 15); jg = x >> 4; }
    bf16x8 v8;
#pragma unroll
    for (int jj = 0; jj < 8; jj++) {
      short val;
      if (e < 64) val = (short)qkvb[(size_t)(row0 + jg * 8 + jj) * QKVW + 512 + h * 64 + e];
      else val = (e == 64) ? (short)0x3F80 : (short)0;
      v8[jj] = val;
    }
    *(bf16x8*)(U + 24576 + ((e >> 4) * 4 + (jg >> 2)) * 512 +
               ((jg & 3) * 16 + (e & 15)) * 8) = v8;
  }
  __syncthreads();

  // ---- phase 2: Y = A · Vp ----
  f32x4 Y[2][5] = {};
#pragma unroll
  for (int kc = 0; kc < 4; kc++) {
    bf16x8 a2[2];
#pragma unroll
    for (int mi = 0; mi < 2; mi++)
      a2[mi] = *(const bf16x8*)(U + 8192 + ((w * 2 + mi) * 4 + kc) * 512 + lane * 8);
#pragma unroll
    for (int nt = 0; nt < 5; nt++) {
      bf16x8 b2 = *(const bf16x8*)(U + 24576 + (nt * 4 + kc) * 512 + lane * 8);
#pragma unroll
      for (int mi = 0; mi < 2; mi++)
        Y[mi][nt] = __builtin_amdgcn_mfma_f32_16x16x32_bf16(a2[mi], b2, Y[mi][nt], 0, 0, 0);
    }
  }
  __syncthreads();  // phase-2 reads done; U[0..36863] free for Qf

  // ---- Qf gen: full 128x288 A-fragments into U[0..36863] (once) ----
#pragma unroll 2
  for (int iter = 0; iter < 18; iter++) {
    int gv = iter * 256 + tid;
    int kt = gv >> 9;
    int w9 = gv & 511;
    int row = ((w9 >> 6) << 4) + (w9 & 15);
    int kh = (w9 >> 4) & 3;
    const unsigned short* qr = Uu + 36864 + row * 17;
    bf16x8 v8;
#pragma unroll
    for (int j = 0; j < 8; j++) {
      int f = kt * 32 + kh * 8 + j;
      float qf;
      if (f == 0) qf = 1.0f;
      else if (f < 17) qf = 0.5f * bf2f(qr[f - 1]);
      else if (f < FDIM) {
        int ix = f - 17;
        qf = C2 * bf2f(qr[ix >> 4]) * bf2f(qr[ix & 15]);
      } else qf = 0.0f;
      v8[j] = (short)f2bf(qf);
    }
    *(bf16x8*)(U + (size_t)gv * 8) = v8;
  }
  __syncthreads();  // Qf complete; phase 3 is barrier-free from here

  // ---- phase 3: Y += Qf · [P|u]; B-fragments DIRECT from global PG ----
  const unsigned short* pgl = PG + ((size_t)bh * NCH + c) * 45 * 512 + lane * 8;
#pragma unroll
  for (int ft = 0; ft < 9; ft++) {
    bf16x8 b3[5];
#pragma unroll
    for (int nt = 0; nt < 5; nt++)
      b3[nt] = *(const bf16x8*)(pgl + (ft * 5 + nt) * 512);
    bf16x8 a3[2];
#pragma unroll
    for (int mi = 0; mi < 2; mi++)
      a3[mi] = *(const bf16x8*)(U + ft * 4096 + (w * 2 + mi) * 512 + lane * 8);
#pragma unroll
    for (int nt = 0; nt < 5; nt++)
#pragma unroll
      for (int mi = 0; mi < 2; mi++)
        Y[mi][nt] = __builtin_amdgcn_mfma_f32_16x16x32_bf16(a3[mi], b3[nt], Y[mi][nt], 0, 0, 0);
  }

  // ---- epilogue: den from ones column (nt=4, col 0), scale, store bf16 ----
  const int cl = lane & 15, r0q = (lane >> 4) * 4;
  if (cl == 0) {
#pragma unroll
    for (int mi = 0; mi < 2; mi++)
#pragma unroll
      for (int reg = 0; reg < 4; reg++)
        denL[(w * 2 + mi) * 16 + r0q + reg] = Y[mi][4][reg];
  }
  __syncthreads();
#pragma unroll
  for (int mi = 0; mi < 2; mi++) {
    float invd[4];
#pragma unroll
    for (int reg = 0; reg < 4; reg++)
      invd[reg] = 1.0f / (denL[(w * 2 + mi) * 16 + r0q + reg] + 1e-12f);
#pragma unroll
    for (int nt = 0; nt < 4; nt++)
#pragma unroll
      for (int reg = 0; reg < 4; reg++) {
        int i = (w * 2 + mi) * 16 + r0q + reg;
        int e = nt * 16 + cl;
        ybuf[(size_t)(row0 + i) * (NH * DV) + h * DV + e] =
            f2bf(Y[mi][nt][reg] * invd[reg]);
      }
  }
}

// ---------------------------------------------------------------------------
extern "C" void kernel_launch(void* const* d_in, const int* in_sizes, int n_in,
                              void* d_out, int out_size, void* d_ws, size_t ws_size,
                              hipStream_t stream) {
  const float* hs = (const float*)d_in[0];
  const float* Wq = (const float*)d_in[1];
  const float* Wk = (const float*)d_in[2];
  const float* Wv = (const float*)d_in[3];
  const float* Wo = (const float*)d_in[4];
  float* out = (float*)d_out;

  // workspace layout (~73 MB)
  unsigned short* qkvb  = (unsigned short*)d_ws;            // 4096 x 1536 bf16 (q|k|v)
  unsigned short* Sfrag = qkvb + (size_t)ROWS * QKVW;       // 512 x 45 x 512 bf16
  unsigned short* PG    = Sfrag + (size_t)NBC * 45 * 512;   // 512 x 45 x 512 bf16
  unsigned short* hsb   = PG + (size_t)NBC * 45 * 512;      // 4096 x 1024 bf16
  unsigned short* yb    = hsb;  // alias: hsb dead after projection GEMM
  unsigned short* wqt   = hsb + (size_t)ROWS * DMODEL;      // 256 x 1024 bf16
  unsigned short* wkt   = wqt + (size_t)(NH * DQK) * DMODEL;
  unsigned short* wvt   = wkt + (size_t)(NH * DQK) * DMODEL; // contiguous -> 1536x1024
  unsigned short* wot   = wvt + (size_t)(NH * DV) * DMODEL;  // 1024 x 1024 bf16

  // casts / transposes
  cast4<<<dim3((ROWS * DMODEL / 4 + 255) / 256), 256, 0, stream>>>(hs, hsb, ROWS * DMODEL / 4);
  transpose_cast_all<<<dim3(32, 32, 4), 256, 0, stream>>>(Wq, Wk, Wv, Wo, wqt, wkt, wvt, wot);

  // fused q|k|v projection (MFMA, bf16 out, N=1536)
  gemm_mfma<unsigned short><<<dim3(QKVW / 128, ROWS / 128), 256, 0, stream>>>(
      hsb, wqt, qkvb, ROWS, QKVW, DMODEL);

  // chunked causal linear attention
  chunk_sums_mfma<<<dim3(NCH, NBH), 256, 0, stream>>>(qkvb, Sfrag);
  prefix_scan_frag<<<dim3(45, NBH), 64, 0, stream>>>(Sfrag, PG);
  attn_mfma<<<dim3(NCH, NBH), 256, 0, stream>>>(qkvb, PG, yb);

  // output projection (MFMA, fp32 out)
  gemm_mfma<float><<<dim3(DMODEL / 128, ROWS / 128), 256, 0, stream>>>(
      yb, wot, out, ROWS, DMODEL, DMODEL);
}

// Round 10
// 196.689 us; speedup vs baseline: 1.4037x; 1.0433x over previous
//
#include <hip/hip_runtime.h>
#include <hip/hip_bf16.h>

// Problem constants
#define BATCH 2
#define LSEQ 2048
#define DMODEL 1024
#define NH 16
#define DQK 16
#define DV 64
#define FDIM 273            // 1 + 16 + 256
#define CHUNK 128
#define NCH (LSEQ / CHUNK)  // 16 chunks per batch row
#define ROWS (BATCH * LSEQ) // 4096
#define NBH (BATCH * NH)    // 32
#define NBC (NBH * NCH)     // 512 (b,h,chunk) units
#define QKVW 1536           // fused qkv row stride (bf16)
#define C2 0.17677669529663687f  // 1/(4*sqrt(2))

typedef short bf16x8 __attribute__((ext_vector_type(8)));
typedef float f32x4 __attribute__((ext_vector_type(4)));

__device__ __forceinline__ unsigned short f2bf(float f) {
  __hip_bfloat16 h = __float2bfloat16(f);
  unsigned short u; __builtin_memcpy(&u, &h, 2); return u;
}
__device__ __forceinline__ float bf2f(unsigned short u) {
  unsigned int v = (unsigned int)u << 16; float f; __builtin_memcpy(&f, &v, 4); return f;
}

__device__ __forceinline__ void storeC(float* C, size_t off, float v) { C[off] = v; }
__device__ __forceinline__ void storeC(unsigned short* C, size_t off, float v) {
  C[off] = f2bf(v);
}

// ---------------------------------------------------------------------------
// prep: z=0..3 -> W (KxN fp32) transpose+cast to Wt (NxK bf16);
//       z=4    -> hs fp32 -> bf16 cast (4 float4 per thread).
// wqt/wkt/wvt land contiguously -> combined 1536x1024 QKV weight.
// ---------------------------------------------------------------------------
__global__ __launch_bounds__(256) void prep(
    const float* __restrict__ hs,
    const float* __restrict__ Wq, const float* __restrict__ Wk,
    const float* __restrict__ Wv, const float* __restrict__ Wo,
    unsigned short* __restrict__ hsb,
    unsigned short* __restrict__ wqt, unsigned short* __restrict__ wkt,
    unsigned short* __restrict__ wvt, unsigned short* __restrict__ wot) {
  __shared__ float t[32][33];
  if (blockIdx.z == 4) {
    int bid = blockIdx.y * 32 + blockIdx.x;
    const float4* in4 = (const float4*)hs;
#pragma unroll
    for (int k = 0; k < 4; k++) {
      int i = bid * 1024 + k * 256 + threadIdx.x;
      float4 v = in4[i];
      ushort4 o = {f2bf(v.x), f2bf(v.y), f2bf(v.z), f2bf(v.w)};
      ((ushort4*)hsb)[i] = o;
    }
    return;
  }
  const float* W; unsigned short* Wt; int N;
  switch (blockIdx.z) {
    case 0: W = Wq; Wt = wqt; N = 256; break;
    case 1: W = Wk; Wt = wkt; N = 256; break;
    case 2: W = Wv; Wt = wvt; N = 1024; break;
    default: W = Wo; Wt = wot; N = 1024; break;
  }
  const int nb = blockIdx.x * 32;
  if (nb >= N) return;
  const int kb = blockIdx.y * 32;
  const int tx = threadIdx.x & 31, ty4 = (threadIdx.x >> 5) * 4;
#pragma unroll
  for (int r = 0; r < 4; r++)
    t[ty4 + r][tx] = W[(size_t)(kb + ty4 + r) * N + nb + tx];
  __syncthreads();
#pragma unroll
  for (int r = 0; r < 4; r++)
    Wt[(size_t)(nb + ty4 + r) * DMODEL + kb + tx] = f2bf(t[tx][ty4 + r]);
}

// ---------------------------------------------------------------------------
// MFMA GEMM, BM=64 x BN=128 tile (2-3 blocks/CU for our shapes -> latency
// overlap that the 128x128 tile's 1 block/CU could not get), BK=32,
// 256 threads = 4 waves, each wave a 32x64 quadrant (2x4 MFMA tiles).
// C(MxN) = A(MxK bf16) @ Bt(NxK bf16)^T, C fp32 or bf16.
// ---------------------------------------------------------------------------
template <typename CT>
__global__ __launch_bounds__(256) void gemm_mfma64(
    const unsigned short* __restrict__ A, const unsigned short* __restrict__ Bt,
    CT* __restrict__ C, int M, int N, int K) {
  __shared__ unsigned short As[256 * 8];  // 4 KB
  __shared__ unsigned short Bs[512 * 8];  // 8 KB
  const int tid = threadIdx.x;
  const int bm = blockIdx.y * 64, bn = blockIdx.x * 128;
  const int lane = tid & 63;
  const int w = tid >> 6;
  const int qr = (w >> 1) * 32, qc = (w & 1) * 64;
  f32x4 acc[2][4] = {};

  for (int k0 = 0; k0 < K; k0 += 32) {
#pragma unroll
    for (int j = 0; j < 3; ++j) {
      int c = j * 256 + tid;
      const unsigned short* gp;
      unsigned short* lp;
      if (c < 256) {
        int cc = c;
        int row = ((cc >> 6) << 4) + (cc & 15);
        int kh = (cc >> 4) & 3;
        gp = A + (size_t)(bm + row) * K + k0 + kh * 8; lp = As + cc * 8;
      } else {
        int cc = c - 256;
        int row = ((cc >> 6) << 4) + (cc & 15);
        int kh = (cc >> 4) & 3;
        gp = Bt + (size_t)(bn + row) * K + k0 + kh * 8; lp = Bs + cc * 8;
      }
      __builtin_amdgcn_global_load_lds(
          (const __attribute__((address_space(1))) unsigned int*)(const void*)gp,
          (__attribute__((address_space(3))) unsigned int*)lp, 16, 0, 0);
    }
    __syncthreads();
    bf16x8 a[2], b[4];
#pragma unroll
    for (int i = 0; i < 2; ++i)
      a[i] = *(const bf16x8*)(As + ((qr >> 4) + i) * 512 + lane * 8);
#pragma unroll
    for (int i = 0; i < 4; ++i)
      b[i] = *(const bf16x8*)(Bs + ((qc >> 4) + i) * 512 + lane * 8);
#pragma unroll
    for (int i = 0; i < 2; ++i)
#pragma unroll
      for (int jj = 0; jj < 4; ++jj)
        acc[i][jj] = __builtin_amdgcn_mfma_f32_16x16x32_bf16(a[i], b[jj], acc[i][jj], 0, 0, 0);
    __syncthreads();
  }
  const int cn = lane & 15, r0 = (lane >> 4) * 4;
#pragma unroll
  for (int i = 0; i < 2; ++i)
#pragma unroll
    for (int jj = 0; jj < 4; ++jj) {
      size_t base = (size_t)(bm + qr + i * 16 + r0) * N + bn + qc + jj * 16 + cn;
#pragma unroll
      for (int r = 0; r < 4; ++r) storeC(C, base + (size_t)r * N, acc[i][jj][r]);
    }
}

// ---------------------------------------------------------------------------
// Pass 1 (MFMA): [S_c|u_c] = Kf^T[288x128] @ [V|1|pad][128x80] per (b,h,chunk),
// emitted DIRECTLY in the PG bf16 B-fragment layout (45 tiles x 512).
// ---------------------------------------------------------------------------
__global__ __launch_bounds__(256) void chunk_sums_mfma(
    const unsigned short* __restrict__ qkvb, unsigned short* __restrict__ Sfrag) {
  const int c = blockIdx.x, bh = blockIdx.y;
  const int b = bh >> 4, h = bh & 15;
  const int tid = threadIdx.x;
  const int lane = tid & 63, w = tid >> 6;
  const int row0 = b * LSEQ + c * CHUNK;

  __shared__ float ksT[16 * 132];   // k transposed [d][i], stride 132
  __shared__ short SH[56 * 512];    // Vp[0..20*512) | Kf0 | Kf1 ; epi: Sfrag stage
  short* Vp = SH;
  short* Kf0 = SH + 20 * 512;
  short* Kf1 = SH + 38 * 512;

  // ---- stage ksT (fp32 from bf16 k; stride 132 -> 2-way-free banks) ----
  {
    int i = tid >> 1, d0 = (tid & 1) * 8;
    bf16x8 k8 = *(const bf16x8*)(qkvb + (size_t)(row0 + i) * QKVW + 256 + h * 16 + d0);
#pragma unroll
    for (int j = 0; j < 8; j++) ksT[(d0 + j) * 132 + i] = bf2f((unsigned short)k8[j]);
  }
  // ---- stage Vp = [V | 1 | 0-pad] (B-operand, N=80, K=128), bf16 copies ----
  for (int t = tid; t < 1280; t += 256) {
    int e, jg;
    if (t < 1024) { e = t & 63; jg = t >> 6; }
    else { int x = t - 1024; e = 64 + (x & 15); jg = x >> 4; }
    bf16x8 v8;
#pragma unroll
    for (int jj = 0; jj < 8; jj++) {
      short val;
      if (e < 64) val = (short)qkvb[(size_t)(row0 + jg * 8 + jj) * QKVW + 512 + h * 64 + e];
      else val = (e == 64) ? (short)0x3F80 : (short)0;
      v8[jj] = val;
    }
    *(bf16x8*)(Vp + ((e >> 4) * 4 + (jg >> 2)) * 512 + ((jg & 3) * 16 + (e & 15)) * 8) = v8;
  }
  __syncthreads();

  // ---- kf-slice generator: rows i0..i0+31 of Kf^T into Kf buf ----
  auto gen = [&](int kt, short* dst) {
    for (int o = tid; o < 1152; o += 256) {
      int mt = o >> 6, w6 = o & 63;
      int kh = w6 >> 4, m = w6 & 15;
      int f = mt * 16 + m;
      int i0 = kt * 32 + kh * 8;
      bf16x8 v8;
      if (f == 0) {
#pragma unroll
        for (int j = 0; j < 8; j++) v8[j] = (short)0x3F80;
      } else if (f < 17) {
        const float* ka = &ksT[(f - 1) * 132 + i0];
        float4 a0 = *(const float4*)ka, a1 = *(const float4*)(ka + 4);
        v8[0] = (short)f2bf(0.5f * a0.x); v8[1] = (short)f2bf(0.5f * a0.y);
        v8[2] = (short)f2bf(0.5f * a0.z); v8[3] = (short)f2bf(0.5f * a0.w);
        v8[4] = (short)f2bf(0.5f * a1.x); v8[5] = (short)f2bf(0.5f * a1.y);
        v8[6] = (short)f2bf(0.5f * a1.z); v8[7] = (short)f2bf(0.5f * a1.w);
      } else if (f < FDIM) {
        int ix = f - 17;
        const float* ka = &ksT[(ix >> 4) * 132 + i0];
        const float* kb2 = &ksT[(ix & 15) * 132 + i0];
        float4 a0 = *(const float4*)ka, a1 = *(const float4*)(ka + 4);
        float4 b0 = *(const float4*)kb2, b1 = *(const float4*)(kb2 + 4);
        v8[0] = (short)f2bf(C2 * a0.x * b0.x); v8[1] = (short)f2bf(C2 * a0.y * b0.y);
        v8[2] = (short)f2bf(C2 * a0.z * b0.z); v8[3] = (short)f2bf(C2 * a0.w * b0.w);
        v8[4] = (short)f2bf(C2 * a1.x * b1.x); v8[5] = (short)f2bf(C2 * a1.y * b1.y);
        v8[6] = (short)f2bf(C2 * a1.z * b1.z); v8[7] = (short)f2bf(C2 * a1.w * b1.w);
      } else {
#pragma unroll
        for (int j = 0; j < 8; j++) v8[j] = 0;
      }
      *(bf16x8*)(dst + mt * 512 + (kh * 16 + m) * 8) = v8;
    }
  };

  gen(0, Kf0);
  __syncthreads();

  f32x4 acc[5][5] = {};
  const int nmt = (w < 2) ? 5 : 4;
  for (int kt = 0; kt < 4; kt++) {
    short* cur = (kt & 1) ? Kf1 : Kf0;
    if (kt < 3) gen(kt + 1, (kt & 1) ? Kf0 : Kf1);
    bf16x8 bv[5];
#pragma unroll
    for (int nt = 0; nt < 5; nt++)
      bv[nt] = *(const bf16x8*)(Vp + (nt * 4 + kt) * 512 + lane * 8);
#pragma unroll
    for (int t2 = 0; t2 < 5; t2++) {
      if (t2 < nmt) {  // wave-uniform; keeps acc indices compile-time (R5 lesson)
        int mt = w + t2 * 4;
        bf16x8 av = *(const bf16x8*)(cur + mt * 512 + lane * 8);
#pragma unroll
        for (int nt = 0; nt < 5; nt++)
          acc[t2][nt] = __builtin_amdgcn_mfma_f32_16x16x32_bf16(av, bv[nt], acc[t2][nt], 0, 0, 0);
      }
    }
    __syncthreads();
  }

  // ---- epilogue: scatter acc -> SH in fragment layout, then bulk store ----
  const int cl = lane & 15, r0q = (lane >> 4) * 4;
#pragma unroll
  for (int t2 = 0; t2 < 5; t2++) {
    if (t2 < nmt) {
      int mt = w + t2 * 4;
#pragma unroll
      for (int reg = 0; reg < 4; reg++) {
        int f = mt * 16 + r0q + reg;  // 0..287; f>=FDIM values are exact 0
#pragma unroll
        for (int nt = 0; nt < 5; nt++) {
          int e = nt * 16 + cl;       // 0..79; e>64 values are exact 0
          SH[((f >> 5) * 5 + nt) * 512 + (((f >> 3) & 3) * 16 + (e & 15)) * 8 + (f & 7)] =
              (short)f2bf(acc[t2][nt][reg]);
        }
      }
    }
  }
  __syncthreads();
  unsigned short* dst = Sfrag + ((size_t)bh * NCH + c) * 45 * 512;
  for (int o = tid; o < 2880; o += 256)
    *(bf16x8*)(dst + o * 8) = *(const bf16x8*)(SH + o * 8);
}

// ---------------------------------------------------------------------------
// Pass 2: exclusive prefix over chunks in fragment layout, fully vectorized.
// ---------------------------------------------------------------------------
__global__ __launch_bounds__(64) void prefix_scan_frag(
    const unsigned short* __restrict__ Sfrag, unsigned short* __restrict__ PG) {
  const int kt5 = blockIdx.x, bh = blockIdx.y;
  const int lane = threadIdx.x;
  float run[8] = {0.f, 0.f, 0.f, 0.f, 0.f, 0.f, 0.f, 0.f};
  const size_t base = ((size_t)bh * NCH * 45 + kt5) * 512 + lane * 8;
#pragma unroll
  for (int cc = 0; cc < NCH; cc++) {
    size_t a = base + (size_t)cc * 45 * 512;
    bf16x8 s8 = *(const bf16x8*)(Sfrag + a);
    bf16x8 o8;
#pragma unroll
    for (int j = 0; j < 8; j++) {
      o8[j] = (short)f2bf(run[j]);
      run[j] += bf2f((unsigned short)s8[j]);
    }
    *(bf16x8*)(PG + a) = o8;
  }
}

// ---------------------------------------------------------------------------
// Pass 3 (MFMA): per-(b,h,chunk) outputs -> bf16 y.
// ---------------------------------------------------------------------------
__global__ __launch_bounds__(256) void attn_mfma(
    const unsigned short* __restrict__ qkvb, const unsigned short* __restrict__ PG,
    unsigned short* __restrict__ ybuf) {
  const int c = blockIdx.x, bh = blockIdx.y;
  const int b = bh >> 4, h = bh & 15;
  const int tid = threadIdx.x;
  const int lane = tid & 63, w = tid >> 6;
  const int row0 = b * LSEQ + c * CHUNK;

  __shared__ short U[39040];
  __shared__ float denL[128];
  unsigned short* Uu = (unsigned short*)U;

  // ---- stage qsB (bf16 q rows, stride 17 -> conflict-free gathers) ----
  {
    int i = tid >> 1, d0 = (tid & 1) * 8;
    bf16x8 q8 = *(const bf16x8*)(qkvb + (size_t)(row0 + i) * QKVW + h * 16 + d0);
    unsigned short* qd = Uu + 36864 + i * 17 + d0;
#pragma unroll
    for (int j = 0; j < 8; j++) qd[j] = (unsigned short)q8[j];
  }
  // ---- stage Qb, Kb (bf16 fragments, K padded to 32 with zeros) ----
  for (int t = tid; t < 1024; t += 256) {
    int isK = t >> 9;
    int tt = t & 511;
    int i = tt >> 2, kh = tt & 3;
    bf16x8 v8 = {0, 0, 0, 0, 0, 0, 0, 0};
    if (kh < 2)
      v8 = *(const bf16x8*)(qkvb + (size_t)(row0 + i) * QKVW + isK * 256 + h * 16 + kh * 8);
    *(bf16x8*)(U + isK * 4096 + (i >> 4) * 512 + (kh * 16 + (i & 15)) * 8) = v8;
  }
  __syncthreads();

  // ---- phase 1: S = Q K^T -> poly+mask -> Am (no mid-sync: Am region
  //      U[8192..24575] is disjoint from Qb/Kb U[0..8191]) ----
  {
    bf16x8 aq[2];
#pragma unroll
    for (int mi = 0; mi < 2; mi++)
      aq[mi] = *(const bf16x8*)(U + (w * 2 + mi) * 512 + lane * 8);
    f32x4 S[2][8] = {};
#pragma unroll
    for (int nt = 0; nt < 8; nt++) {
      bf16x8 bk = *(const bf16x8*)(U + 4096 + nt * 512 + lane * 8);
#pragma unroll
      for (int mi = 0; mi < 2; mi++)
        S[mi][nt] = __builtin_amdgcn_mfma_f32_16x16x32_bf16(aq[mi], bk, S[mi][nt], 0, 0, 0);
    }
    const int cl = lane & 15, r0q = (lane >> 4) * 4;
#pragma unroll
    for (int mi = 0; mi < 2; mi++)
#pragma unroll
      for (int nt = 0; nt < 8; nt++)
#pragma unroll
        for (int reg = 0; reg < 4; reg++) {
          int i = (w * 2 + mi) * 16 + r0q + reg;
          int j = nt * 16 + cl;
          float s = S[mi][nt][reg];
          float aij = (j <= i) ? fmaf(s, fmaf(s, 0.03125f, 0.25f), 1.0f) : 0.0f;
          U[8192 + ((i >> 4) * 4 + (j >> 5)) * 512 +
            (((j >> 3) & 3) * 16 + (i & 15)) * 8 + (j & 7)] = (short)f2bf(aij);
        }
  }
  // ---- stage Vp = [V | 1 | 0-pad] (B-operand, N=80, K=128) ----
  for (int t = tid; t < 1280; t += 256) {
    int e, jg;
    if (t < 1024) { e = t & 63; jg = t >> 6; }
    else { int x = t - 1024; e = 64 + (x & 15); jg = x >> 4; }
    bf16x8 v8;
#pragma unroll
    for (int jj = 0; jj < 8; jj++) {
      short val;
      if (e < 64) val = (short)qkvb[(size_t)(row0 + jg * 8 + jj) * QKVW + 512 + h * 64 + e];
      else val = (e == 64) ? (short)0x3F80 : (short)0;
      v8[jj] = val;
    }
    *(bf16x8*)(U + 24576 + ((e >> 4) * 4 + (jg >> 2)) * 512 +
               ((jg & 3) * 16 + (e & 15)) * 8) = v8;
  }
  __syncthreads();

  // ---- phase 2: Y = A · Vp ----
  f32x4 Y[2][5] = {};
#pragma unroll
  for (int kc = 0; kc < 4; kc++) {
    bf16x8 a2[2];
#pragma unroll
    for (int mi = 0; mi < 2; mi++)
      a2[mi] = *(const bf16x8*)(U + 8192 + ((w * 2 + mi) * 4 + kc) * 512 + lane * 8);
#pragma unroll
    for (int nt = 0; nt < 5; nt++) {
      bf16x8 b2 = *(const bf16x8*)(U + 24576 + (nt * 4 + kc) * 512 + lane * 8);
#pragma unroll
      for (int mi = 0; mi < 2; mi++)
        Y[mi][nt] = __builtin_amdgcn_mfma_f32_16x16x32_bf16(a2[mi], b2, Y[mi][nt], 0, 0, 0);
    }
  }
  __syncthreads();  // phase-2 reads done; U[0..36863] free for Qf

  // ---- Qf gen: full 128x288 A-fragments into U[0..36863] (once) ----
#pragma unroll 2
  for (int iter = 0; iter < 18; iter++) {
    int gv = iter * 256 + tid;
    int kt = gv >> 9;
    int w9 = gv & 511;
    int row = ((w9 >> 6) << 4) + (w9 & 15);
    int kh = (w9 >> 4) & 3;
    const unsigned short* qr = Uu + 36864 + row * 17;
    bf16x8 v8;
#pragma unroll
    for (int j = 0; j < 8; j++) {
      int f = kt * 32 + kh * 8 + j;
      float qf;
      if (f == 0) qf = 1.0f;
      else if (f < 17) qf = 0.5f * bf2f(qr[f - 1]);
      else if (f < FDIM) {
        int ix = f - 17;
        qf = C2 * bf2f(qr[ix >> 4]) * bf2f(qr[ix & 15]);
      } else qf = 0.0f;
      v8[j] = (short)f2bf(qf);
    }
    *(bf16x8*)(U + (size_t)gv * 8) = v8;
  }
  __syncthreads();  // Qf complete; phase 3 is barrier-free from here

  // ---- phase 3: Y += Qf · [P|u]; B-fragments DIRECT from global PG ----
  const unsigned short* pgl = PG + ((size_t)bh * NCH + c) * 45 * 512 + lane * 8;
#pragma unroll
  for (int ft = 0; ft < 9; ft++) {
    bf16x8 b3[5];
#pragma unroll
    for (int nt = 0; nt < 5; nt++)
      b3[nt] = *(const bf16x8*)(pgl + (ft * 5 + nt) * 512);
    bf16x8 a3[2];
#pragma unroll
    for (int mi = 0; mi < 2; mi++)
      a3[mi] = *(const bf16x8*)(U + ft * 4096 + (w * 2 + mi) * 512 + lane * 8);
#pragma unroll
    for (int nt = 0; nt < 5; nt++)
#pragma unroll
      for (int mi = 0; mi < 2; mi++)
        Y[mi][nt] = __builtin_amdgcn_mfma_f32_16x16x32_bf16(a3[mi], b3[nt], Y[mi][nt], 0, 0, 0);
  }

  // ---- epilogue: den from ones column (nt=4, col 0), scale, store bf16 ----
  const int cl = lane & 15, r0q = (lane >> 4) * 4;
  if (cl == 0) {
#pragma unroll
    for (int mi = 0; mi < 2; mi++)
#pragma unroll
      for (int reg = 0; reg < 4; reg++)
        denL[(w * 2 + mi) * 16 + r0q + reg] = Y[mi][4][reg];
  }
  __syncthreads();
#pragma unroll
  for (int mi = 0; mi < 2; mi++) {
    float invd[4];
#pragma unroll
    for (int reg = 0; reg < 4; reg++)
      invd[reg] = 1.0f / (denL[(w * 2 + mi) * 16 + r0q + reg] + 1e-12f);
#pragma unroll
    for (int nt = 0; nt < 4; nt++)
#pragma unroll
      for (int reg = 0; reg < 4; reg++) {
        int i = (w * 2 + mi) * 16 + r0q + reg;
        int e = nt * 16 + cl;
        ybuf[(size_t)(row0 + i) * (NH * DV) + h * DV + e] =
            f2bf(Y[mi][nt][reg] * invd[reg]);
      }
  }
}

// ---------------------------------------------------------------------------
extern "C" void kernel_launch(void* const* d_in, const int* in_sizes, int n_in,
                              void* d_out, int out_size, void* d_ws, size_t ws_size,
                              hipStream_t stream) {
  const float* hs = (const float*)d_in[0];
  const float* Wq = (const float*)d_in[1];
  const float* Wk = (const float*)d_in[2];
  const float* Wv = (const float*)d_in[3];
  const float* Wo = (const float*)d_in[4];
  float* out = (float*)d_out;

  // workspace layout (~73 MB)
  unsigned short* qkvb  = (unsigned short*)d_ws;            // 4096 x 1536 bf16 (q|k|v)
  unsigned short* Sfrag = qkvb + (size_t)ROWS * QKVW;       // 512 x 45 x 512 bf16
  unsigned short* PG    = Sfrag + (size_t)NBC * 45 * 512;   // 512 x 45 x 512 bf16
  unsigned short* hsb   = PG + (size_t)NBC * 45 * 512;      // 4096 x 1024 bf16
  unsigned short* yb    = hsb;  // alias: hsb dead after projection GEMM
  unsigned short* wqt   = hsb + (size_t)ROWS * DMODEL;      // 256 x 1024 bf16
  unsigned short* wkt   = wqt + (size_t)(NH * DQK) * DMODEL;
  unsigned short* wvt   = wkt + (size_t)(NH * DQK) * DMODEL; // contiguous -> 1536x1024
  unsigned short* wot   = wvt + (size_t)(NH * DV) * DMODEL;  // 1024 x 1024 bf16

  // fused casts + transposes (one launch)
  prep<<<dim3(32, 32, 5), 256, 0, stream>>>(hs, Wq, Wk, Wv, Wo, hsb, wqt, wkt, wvt, wot);

  // fused q|k|v projection (MFMA, bf16 out, N=1536): 768 blocks = 3/CU
  gemm_mfma64<unsigned short><<<dim3(QKVW / 128, ROWS / 64), 256, 0, stream>>>(
      hsb, wqt, qkvb, ROWS, QKVW, DMODEL);

  // chunked causal linear attention
  chunk_sums_mfma<<<dim3(NCH, NBH), 256, 0, stream>>>(qkvb, Sfrag);
  prefix_scan_frag<<<dim3(45, NBH), 64, 0, stream>>>(Sfrag, PG);
  attn_mfma<<<dim3(NCH, NBH), 256, 0, stream>>>(qkvb, PG, yb);

  // output projection (MFMA, fp32 out): 512 blocks = 2/CU
  gemm_mfma64<float><<<dim3(DMODEL / 128, ROWS / 64), 256, 0, stream>>>(
      yb, wot, out, ROWS, DMODEL, DMODEL);
}

// Round 11
// 182.474 us; speedup vs baseline: 1.5130x; 1.0779x over previous
//
#include <hip/hip_runtime.h>
#include <hip/hip_bf16.h>

// Problem constants
#define BATCH 2
#define LSEQ 2048
#define DMODEL 1024
#define NH 16
#define DQK 16
#define DV 64
#define FDIM 273            // 1 + 16 + 256
#define CHUNK 128
#define NCH (LSEQ / CHUNK)  // 16 chunks per batch row
#define ROWS (BATCH * LSEQ) // 4096
#define NBH (BATCH * NH)    // 32
#define NBC (NBH * NCH)     // 512 (b,h,chunk) units
#define QKVW 1536           // fused qkv row stride (bf16)
#define C2 0.17677669529663687f  // 1/(4*sqrt(2))

typedef short bf16x8 __attribute__((ext_vector_type(8)));
typedef float f32x4 __attribute__((ext_vector_type(4)));

__device__ __forceinline__ unsigned short f2bf(float f) {
  __hip_bfloat16 h = __float2bfloat16(f);
  unsigned short u; __builtin_memcpy(&u, &h, 2); return u;
}
__device__ __forceinline__ float bf2f(unsigned short u) {
  unsigned int v = (unsigned int)u << 16; float f; __builtin_memcpy(&f, &v, 4); return f;
}

__device__ __forceinline__ void storeC(float* C, size_t off, float v) { C[off] = v; }
__device__ __forceinline__ void storeC(unsigned short* C, size_t off, float v) {
  C[off] = f2bf(v);
}

// ---------------------------------------------------------------------------
// prep: z=0..3 -> W (KxN fp32) transpose+cast to Wt (NxK bf16);
//       z=4    -> hs fp32 -> bf16 cast.
// wqt/wkt/wvt land contiguously -> combined 1536x1024 QKV weight.
// ---------------------------------------------------------------------------
__global__ __launch_bounds__(256) void prep(
    const float* __restrict__ hs,
    const float* __restrict__ Wq, const float* __restrict__ Wk,
    const float* __restrict__ Wv, const float* __restrict__ Wo,
    unsigned short* __restrict__ hsb,
    unsigned short* __restrict__ wqt, unsigned short* __restrict__ wkt,
    unsigned short* __restrict__ wvt, unsigned short* __restrict__ wot) {
  __shared__ float t[32][33];
  if (blockIdx.z == 4) {
    int bid = blockIdx.y * 32 + blockIdx.x;
    const float4* in4 = (const float4*)hs;
#pragma unroll
    for (int k = 0; k < 4; k++) {
      int i = bid * 1024 + k * 256 + threadIdx.x;
      float4 v = in4[i];
      ushort4 o = {f2bf(v.x), f2bf(v.y), f2bf(v.z), f2bf(v.w)};
      ((ushort4*)hsb)[i] = o;
    }
    return;
  }
  const float* W; unsigned short* Wt; int N;
  switch (blockIdx.z) {
    case 0: W = Wq; Wt = wqt; N = 256; break;
    case 1: W = Wk; Wt = wkt; N = 256; break;
    case 2: W = Wv; Wt = wvt; N = 1024; break;
    default: W = Wo; Wt = wot; N = 1024; break;
  }
  const int nb = blockIdx.x * 32;
  if (nb >= N) return;
  const int kb = blockIdx.y * 32;
  const int tx = threadIdx.x & 31, ty4 = (threadIdx.x >> 5) * 4;
#pragma unroll
  for (int r = 0; r < 4; r++)
    t[ty4 + r][tx] = W[(size_t)(kb + ty4 + r) * N + nb + tx];
  __syncthreads();
#pragma unroll
  for (int r = 0; r < 4; r++)
    Wt[(size_t)(nb + ty4 + r) * DMODEL + kb + tx] = f2bf(t[tx][ty4 + r]);
}

// ---------------------------------------------------------------------------
// MFMA GEMM, BM=64 x BN=128 tile, BK=32, 256 threads = 4 waves,
// each wave a 32x64 quadrant.  C fp32 or bf16.
// ---------------------------------------------------------------------------
template <typename CT>
__global__ __launch_bounds__(256) void gemm_mfma64(
    const unsigned short* __restrict__ A, const unsigned short* __restrict__ Bt,
    CT* __restrict__ C, int M, int N, int K) {
  __shared__ unsigned short As[256 * 8];  // 4 KB
  __shared__ unsigned short Bs[512 * 8];  // 8 KB
  const int tid = threadIdx.x;
  const int bm = blockIdx.y * 64, bn = blockIdx.x * 128;
  const int lane = tid & 63;
  const int w = tid >> 6;
  const int qr = (w >> 1) * 32, qc = (w & 1) * 64;
  f32x4 acc[2][4] = {};

  for (int k0 = 0; k0 < K; k0 += 32) {
#pragma unroll
    for (int j = 0; j < 3; ++j) {
      int c = j * 256 + tid;
      const unsigned short* gp;
      unsigned short* lp;
      if (c < 256) {
        int cc = c;
        int row = ((cc >> 6) << 4) + (cc & 15);
        int kh = (cc >> 4) & 3;
        gp = A + (size_t)(bm + row) * K + k0 + kh * 8; lp = As + cc * 8;
      } else {
        int cc = c - 256;
        int row = ((cc >> 6) << 4) + (cc & 15);
        int kh = (cc >> 4) & 3;
        gp = Bt + (size_t)(bn + row) * K + k0 + kh * 8; lp = Bs + cc * 8;
      }
      __builtin_amdgcn_global_load_lds(
          (const __attribute__((address_space(1))) unsigned int*)(const void*)gp,
          (__attribute__((address_space(3))) unsigned int*)lp, 16, 0, 0);
    }
    __syncthreads();
    bf16x8 a[2], b[4];
#pragma unroll
    for (int i = 0; i < 2; ++i)
      a[i] = *(const bf16x8*)(As + ((qr >> 4) + i) * 512 + lane * 8);
#pragma unroll
    for (int i = 0; i < 4; ++i)
      b[i] = *(const bf16x8*)(Bs + ((qc >> 4) + i) * 512 + lane * 8);
#pragma unroll
    for (int i = 0; i < 2; ++i)
#pragma unroll
      for (int jj = 0; jj < 4; ++jj)
        acc[i][jj] = __builtin_amdgcn_mfma_f32_16x16x32_bf16(a[i], b[jj], acc[i][jj], 0, 0, 0);
    __syncthreads();
  }
  const int cn = lane & 15, r0 = (lane >> 4) * 4;
#pragma unroll
  for (int i = 0; i < 2; ++i)
#pragma unroll
    for (int jj = 0; jj < 4; ++jj) {
      size_t base = (size_t)(bm + qr + i * 16 + r0) * N + bn + qc + jj * 16 + cn;
#pragma unroll
      for (int r = 0; r < 4; ++r) storeC(C, base + (size_t)r * N, acc[i][jj][r]);
    }
}

// ---------------------------------------------------------------------------
// Shared helper: stage [V | 1 | 0-pad] (B-operand fragments, N=80, K=128)
// into Vp via coalesced bf16x8 global loads + LDS scalar scatter.
// (Replaces 40 scalar GLOBAL loads/thread with 32 cheap ds writes — R10 fix.)
// ---------------------------------------------------------------------------
__device__ __forceinline__ void stage_Vp(const unsigned short* __restrict__ qkvb,
                                         int row0, int h, int tid, short* Vp) {
  // V region: 128 rows x 64 e  ->  tiles 0..15
#pragma unroll
  for (int it = 0; it < 4; it++) {
    int t = it * 256 + tid;
    int j = t >> 3, e0 = (t & 7) * 8;
    bf16x8 v8 = *(const bf16x8*)(qkvb + (size_t)(row0 + j) * QKVW + 512 + h * 64 + e0);
    int jg = j >> 3, jj = j & 7;
#pragma unroll
    for (int u = 0; u < 8; u++) {
      int e = e0 + u;
      Vp[((e >> 4) * 4 + (jg >> 2)) * 512 + ((jg & 3) * 16 + (e & 15)) * 8 + jj] =
          v8[u];
    }
  }
  // ones/pad region: tiles 16..19 (e = 64..79)
  {
    int n = tid & 15, jgrp = tid >> 4;
    bf16x8 v8;
#pragma unroll
    for (int u = 0; u < 8; u++) v8[u] = (n == 0) ? (short)0x3F80 : (short)0;
    *(bf16x8*)(Vp + (16 + (jgrp >> 2)) * 512 + ((jgrp & 3) * 16 + n) * 8) = v8;
  }
}

// ---------------------------------------------------------------------------
// Pass 1 (MFMA): [S_c|u_c] = Kf^T[288x128] @ [V|1|pad][128x80] per (b,h,chunk),
// emitted DIRECTLY in the PG bf16 B-fragment layout (45 tiles x 512).
// ---------------------------------------------------------------------------
__global__ __launch_bounds__(256) void chunk_sums_mfma(
    const unsigned short* __restrict__ qkvb, unsigned short* __restrict__ Sfrag) {
  const int c = blockIdx.x, bh = blockIdx.y;
  const int b = bh >> 4, h = bh & 15;
  const int tid = threadIdx.x;
  const int lane = tid & 63, w = tid >> 6;
  const int row0 = b * LSEQ + c * CHUNK;

  __shared__ float ksT[16 * 132];   // k transposed [d][i], stride 132
  __shared__ short SH[56 * 512];    // Vp[0..20*512) | Kf0 | Kf1 ; epi: Sfrag stage
  short* Vp = SH;
  short* Kf0 = SH + 20 * 512;
  short* Kf1 = SH + 38 * 512;

  // ---- stage ksT (fp32 from bf16 k; stride 132 -> 2-way-free banks) ----
  {
    int i = tid >> 1, d0 = (tid & 1) * 8;
    bf16x8 k8 = *(const bf16x8*)(qkvb + (size_t)(row0 + i) * QKVW + 256 + h * 16 + d0);
#pragma unroll
    for (int j = 0; j < 8; j++) ksT[(d0 + j) * 132 + i] = bf2f((unsigned short)k8[j]);
  }
  stage_Vp(qkvb, row0, h, tid, Vp);
  __syncthreads();

  // ---- kf-slice generator: rows i0..i0+31 of Kf^T into Kf buf ----
  auto gen = [&](int kt, short* dst) {
    for (int o = tid; o < 1152; o += 256) {
      int mt = o >> 6, w6 = o & 63;
      int kh = w6 >> 4, m = w6 & 15;
      int f = mt * 16 + m;
      int i0 = kt * 32 + kh * 8;
      bf16x8 v8;
      if (f == 0) {
#pragma unroll
        for (int j = 0; j < 8; j++) v8[j] = (short)0x3F80;
      } else if (f < 17) {
        const float* ka = &ksT[(f - 1) * 132 + i0];
        float4 a0 = *(const float4*)ka, a1 = *(const float4*)(ka + 4);
        v8[0] = (short)f2bf(0.5f * a0.x); v8[1] = (short)f2bf(0.5f * a0.y);
        v8[2] = (short)f2bf(0.5f * a0.z); v8[3] = (short)f2bf(0.5f * a0.w);
        v8[4] = (short)f2bf(0.5f * a1.x); v8[5] = (short)f2bf(0.5f * a1.y);
        v8[6] = (short)f2bf(0.5f * a1.z); v8[7] = (short)f2bf(0.5f * a1.w);
      } else if (f < FDIM) {
        int ix = f - 17;
        const float* ka = &ksT[(ix >> 4) * 132 + i0];
        const float* kb2 = &ksT[(ix & 15) * 132 + i0];
        float4 a0 = *(const float4*)ka, a1 = *(const float4*)(ka + 4);
        float4 b0 = *(const float4*)kb2, b1 = *(const float4*)(kb2 + 4);
        v8[0] = (short)f2bf(C2 * a0.x * b0.x); v8[1] = (short)f2bf(C2 * a0.y * b0.y);
        v8[2] = (short)f2bf(C2 * a0.z * b0.z); v8[3] = (short)f2bf(C2 * a0.w * b0.w);
        v8[4] = (short)f2bf(C2 * a1.x * b1.x); v8[5] = (short)f2bf(C2 * a1.y * b1.y);
        v8[6] = (short)f2bf(C2 * a1.z * b1.z); v8[7] = (short)f2bf(C2 * a1.w * b1.w);
      } else {
#pragma unroll
        for (int j = 0; j < 8; j++) v8[j] = 0;
      }
      *(bf16x8*)(dst + mt * 512 + (kh * 16 + m) * 8) = v8;
    }
  };

  gen(0, Kf0);
  __syncthreads();

  f32x4 acc[5][5] = {};
  const int nmt = (w < 2) ? 5 : 4;
  for (int kt = 0; kt < 4; kt++) {
    short* cur = (kt & 1) ? Kf1 : Kf0;
    if (kt < 3) gen(kt + 1, (kt & 1) ? Kf0 : Kf1);
    bf16x8 bv[5];
#pragma unroll
    for (int nt = 0; nt < 5; nt++)
      bv[nt] = *(const bf16x8*)(Vp + (nt * 4 + kt) * 512 + lane * 8);
#pragma unroll
    for (int t2 = 0; t2 < 5; t2++) {
      if (t2 < nmt) {  // wave-uniform; keeps acc indices compile-time (R5 lesson)
        int mt = w + t2 * 4;
        bf16x8 av = *(const bf16x8*)(cur + mt * 512 + lane * 8);
#pragma unroll
        for (int nt = 0; nt < 5; nt++)
          acc[t2][nt] = __builtin_amdgcn_mfma_f32_16x16x32_bf16(av, bv[nt], acc[t2][nt], 0, 0, 0);
      }
    }
    __syncthreads();
  }

  // ---- epilogue: scatter acc -> SH in fragment layout, then bulk store ----
  const int cl = lane & 15, r0q = (lane >> 4) * 4;
#pragma unroll
  for (int t2 = 0; t2 < 5; t2++) {
    if (t2 < nmt) {
      int mt = w + t2 * 4;
#pragma unroll
      for (int reg = 0; reg < 4; reg++) {
        int f = mt * 16 + r0q + reg;  // 0..287; f>=FDIM values are exact 0
#pragma unroll
        for (int nt = 0; nt < 5; nt++) {
          int e = nt * 16 + cl;       // 0..79; e>64 values are exact 0
          SH[((f >> 5) * 5 + nt) * 512 + (((f >> 3) & 3) * 16 + (e & 15)) * 8 + (f & 7)] =
              (short)f2bf(acc[t2][nt][reg]);
        }
      }
    }
  }
  __syncthreads();
  unsigned short* dst = Sfrag + ((size_t)bh * NCH + c) * 45 * 512;
  for (int o = tid; o < 2880; o += 256)
    *(bf16x8*)(dst + o * 8) = *(const bf16x8*)(SH + o * 8);
}

// ---------------------------------------------------------------------------
// Pass 2: exclusive prefix over chunks in fragment layout, fully vectorized.
// ---------------------------------------------------------------------------
__global__ __launch_bounds__(64) void prefix_scan_frag(
    const unsigned short* __restrict__ Sfrag, unsigned short* __restrict__ PG) {
  const int kt5 = blockIdx.x, bh = blockIdx.y;
  const int lane = threadIdx.x;
  float run[8] = {0.f, 0.f, 0.f, 0.f, 0.f, 0.f, 0.f, 0.f};
  const size_t base = ((size_t)bh * NCH * 45 + kt5) * 512 + lane * 8;
#pragma unroll
  for (int cc = 0; cc < NCH; cc++) {
    size_t a = base + (size_t)cc * 45 * 512;
    bf16x8 s8 = *(const bf16x8*)(Sfrag + a);
    bf16x8 o8;
#pragma unroll
    for (int j = 0; j < 8; j++) {
      o8[j] = (short)f2bf(run[j]);
      run[j] += bf2f((unsigned short)s8[j]);
    }
    *(bf16x8*)(PG + a) = o8;
  }
}

// ---------------------------------------------------------------------------
// Pass 3 (MFMA): per-(b,h,chunk) outputs -> bf16 y.
// LDS union U (73.7 KB, 2 blocks/CU):
//   phase 1: Qb U[0..4095], Kb U[4096..8191]; epi-> Am U[8192..24575]
//   phase 2: Vp U[24576..34815]
//   Qf gen : full 128x288 Qf A-fragments -> U[0..36863] (once, q in VGPRs)
//   phase 3: barrier-free; B-fragments loaded straight from PG (lane*16B).
// ---------------------------------------------------------------------------
__global__ __launch_bounds__(256) void attn_mfma(
    const unsigned short* __restrict__ qkvb, const unsigned short* __restrict__ PG,
    unsigned short* __restrict__ ybuf) {
  const int c = blockIdx.x, bh = blockIdx.y;
  const int b = bh >> 4, h = bh & 15;
  const int tid = threadIdx.x;
  const int lane = tid & 63, w = tid >> 6;
  const int row0 = b * LSEQ + c * CHUNK;

  __shared__ short U[36864];
  __shared__ float denL[128];
  unsigned short* Uu = (unsigned short*)U;

  // ---- issue q-row global loads early (held in VGPRs for Qf gen) ----
  const int qrow = (w >> 1) * 64 + lane;  // 0..127 (wave-uniform halves)
  const int shalf = w & 1;                // wave-uniform feature-half selector
  bf16x8 qa = *(const bf16x8*)(qkvb + (size_t)(row0 + qrow) * QKVW + h * 16);
  bf16x8 qb = *(const bf16x8*)(qkvb + (size_t)(row0 + qrow) * QKVW + h * 16 + 8);

  // ---- stage Qb, Kb (bf16 fragments, K padded to 32 with zeros) ----
  for (int t = tid; t < 1024; t += 256) {
    int isK = t >> 9;
    int tt = t & 511;
    int i = tt >> 2, kh = tt & 3;
    bf16x8 v8 = {0, 0, 0, 0, 0, 0, 0, 0};
    if (kh < 2)
      v8 = *(const bf16x8*)(qkvb + (size_t)(row0 + i) * QKVW + isK * 256 + h * 16 + kh * 8);
    *(bf16x8*)(U + isK * 4096 + (i >> 4) * 512 + (kh * 16 + (i & 15)) * 8) = v8;
  }
  __syncthreads();

  // ---- phase 1: S = Q K^T -> poly+mask -> Am (disjoint regions, no mid-sync)
  {
    bf16x8 aq[2];
#pragma unroll
    for (int mi = 0; mi < 2; mi++)
      aq[mi] = *(const bf16x8*)(U + (w * 2 + mi) * 512 + lane * 8);
    f32x4 S[2][8] = {};
#pragma unroll
    for (int nt = 0; nt < 8; nt++) {
      bf16x8 bk = *(const bf16x8*)(U + 4096 + nt * 512 + lane * 8);
#pragma unroll
      for (int mi = 0; mi < 2; mi++)
        S[mi][nt] = __builtin_amdgcn_mfma_f32_16x16x32_bf16(aq[mi], bk, S[mi][nt], 0, 0, 0);
    }
    const int cl = lane & 15, r0q = (lane >> 4) * 4;
#pragma unroll
    for (int mi = 0; mi < 2; mi++)
#pragma unroll
      for (int nt = 0; nt < 8; nt++)
#pragma unroll
        for (int reg = 0; reg < 4; reg++) {
          int i = (w * 2 + mi) * 16 + r0q + reg;
          int j = nt * 16 + cl;
          float s = S[mi][nt][reg];
          float aij = (j <= i) ? fmaf(s, fmaf(s, 0.03125f, 0.25f), 1.0f) : 0.0f;
          U[8192 + ((i >> 4) * 4 + (j >> 5)) * 512 +
            (((j >> 3) & 3) * 16 + (i & 15)) * 8 + (j & 7)] = (short)f2bf(aij);
        }
  }
  // ---- stage Vp (coalesced loads + LDS scatter) ----
  stage_Vp(qkvb, row0, h, tid, U + 24576);
  __syncthreads();

  // ---- phase 2: Y = A · Vp ----
  f32x4 Y[2][5] = {};
#pragma unroll
  for (int kc = 0; kc < 4; kc++) {
    bf16x8 a2[2];
#pragma unroll
    for (int mi = 0; mi < 2; mi++)
      a2[mi] = *(const bf16x8*)(U + 8192 + ((w * 2 + mi) * 4 + kc) * 512 + lane * 8);
#pragma unroll
    for (int nt = 0; nt < 5; nt++) {
      bf16x8 b2 = *(const bf16x8*)(U + 24576 + (nt * 4 + kc) * 512 + lane * 8);
#pragma unroll
      for (int mi = 0; mi < 2; mi++)
        Y[mi][nt] = __builtin_amdgcn_mfma_f32_16x16x32_bf16(a2[mi], b2, Y[mi][nt], 0, 0, 0);
    }
  }
  __syncthreads();  // phase-2 reads done; U[0..36863] free for Qf

  // ---- Qf gen: thread-owns-row, q in VGPRs, one mul per feature ----
  {
    float qv[16], cq[16];
#pragma unroll
    for (int j = 0; j < 8; j++) {
      qv[j] = bf2f((unsigned short)qa[j]);
      qv[8 + j] = bf2f((unsigned short)qb[j]);
    }
#pragma unroll
    for (int j = 0; j < 16; j++) cq[j] = C2 * qv[j];
    unsigned short* qbase = Uu + (qrow >> 4) * 512 + (qrow & 15) * 8;
    if (shalf == 0) {
#pragma unroll
      for (int vk = 0; vk < 18; vk++) {
        bf16x8 v8;
#pragma unroll
        for (int j = 0; j < 8; j++) {
          int f = vk * 8 + j;
          float qf;
          if (f == 0) qf = 1.0f;
          else if (f < 17) qf = 0.5f * qv[f - 1];
          else { int ix = f - 17; qf = cq[ix >> 4] * qv[ix & 15]; }
          v8[j] = (short)f2bf(qf);
        }
        *(bf16x8*)(qbase + (vk >> 2) * 4096 + (vk & 3) * 128) = v8;
      }
    } else {
#pragma unroll
      for (int vk = 18; vk < 36; vk++) {
        bf16x8 v8;
#pragma unroll
        for (int j = 0; j < 8; j++) {
          int f = vk * 8 + j;
          float qf;
          if (f < FDIM) { int ix = f - 17; qf = cq[ix >> 4] * qv[ix & 15]; }
          else qf = 0.0f;
          v8[j] = (short)f2bf(qf);
        }
        *(bf16x8*)(qbase + (vk >> 2) * 4096 + (vk & 3) * 128) = v8;
      }
    }
  }
  __syncthreads();  // Qf complete; phase 3 is barrier-free from here

  // ---- phase 3: Y += Qf · [P|u]; B-fragments DIRECT from global PG ----
  const unsigned short* pgl = PG + ((size_t)bh * NCH + c) * 45 * 512 + lane * 8;
#pragma unroll
  for (int ft = 0; ft < 9; ft++) {
    bf16x8 b3[5];
#pragma unroll
    for (int nt = 0; nt < 5; nt++)
      b3[nt] = *(const bf16x8*)(pgl + (ft * 5 + nt) * 512);
    bf16x8 a3[2];
#pragma unroll
    for (int mi = 0; mi < 2; mi++)
      a3[mi] = *(const bf16x8*)(U + ft * 4096 + (w * 2 + mi) * 512 + lane * 8);
#pragma unroll
    for (int nt = 0; nt < 5; nt++)
#pragma unroll
      for (int mi = 0; mi < 2; mi++)
        Y[mi][nt] = __builtin_amdgcn_mfma_f32_16x16x32_bf16(a3[mi], b3[nt], Y[mi][nt], 0, 0, 0);
  }

  // ---- epilogue: den from ones column (nt=4, col 0), scale, store bf16 ----
  const int cl = lane & 15, r0q = (lane >> 4) * 4;
  if (cl == 0) {
#pragma unroll
    for (int mi = 0; mi < 2; mi++)
#pragma unroll
      for (int reg = 0; reg < 4; reg++)
        denL[(w * 2 + mi) * 16 + r0q + reg] = Y[mi][4][reg];
  }
  __syncthreads();
#pragma unroll
  for (int mi = 0; mi < 2; mi++) {
    float invd[4];
#pragma unroll
    for (int reg = 0; reg < 4; reg++)
      invd[reg] = 1.0f / (denL[(w * 2 + mi) * 16 + r0q + reg] + 1e-12f);
#pragma unroll
    for (int nt = 0; nt < 4; nt++)
#pragma unroll
      for (int reg = 0; reg < 4; reg++) {
        int i = (w * 2 + mi) * 16 + r0q + reg;
        int e = nt * 16 + cl;
        ybuf[(size_t)(row0 + i) * (NH * DV) + h * DV + e] =
            f2bf(Y[mi][nt][reg] * invd[reg]);
      }
  }
}

// ---------------------------------------------------------------------------
extern "C" void kernel_launch(void* const* d_in, const int* in_sizes, int n_in,
                              void* d_out, int out_size, void* d_ws, size_t ws_size,
                              hipStream_t stream) {
  const float* hs = (const float*)d_in[0];
  const float* Wq = (const float*)d_in[1];
  const float* Wk = (const float*)d_in[2];
  const float* Wv = (const float*)d_in[3];
  const float* Wo = (const float*)d_in[4];
  float* out = (float*)d_out;

  // workspace layout (~73 MB)
  unsigned short* qkvb  = (unsigned short*)d_ws;            // 4096 x 1536 bf16 (q|k|v)
  unsigned short* Sfrag = qkvb + (size_t)ROWS * QKVW;       // 512 x 45 x 512 bf16
  unsigned short* PG    = Sfrag + (size_t)NBC * 45 * 512;   // 512 x 45 x 512 bf16
  unsigned short* hsb   = PG + (size_t)NBC * 45 * 512;      // 4096 x 1024 bf16
  unsigned short* yb    = hsb;  // alias: hsb dead after projection GEMM
  unsigned short* wqt   = hsb + (size_t)ROWS * DMODEL;      // 256 x 1024 bf16
  unsigned short* wkt   = wqt + (size_t)(NH * DQK) * DMODEL;
  unsigned short* wvt   = wkt + (size_t)(NH * DQK) * DMODEL; // contiguous -> 1536x1024
  unsigned short* wot   = wvt + (size_t)(NH * DV) * DMODEL;  // 1024 x 1024 bf16

  // fused casts + transposes (one launch)
  prep<<<dim3(32, 32, 5), 256, 0, stream>>>(hs, Wq, Wk, Wv, Wo, hsb, wqt, wkt, wvt, wot);

  // fused q|k|v projection (MFMA, bf16 out, N=1536): 768 blocks = 3/CU
  gemm_mfma64<unsigned short><<<dim3(QKVW / 128, ROWS / 64), 256, 0, stream>>>(
      hsb, wqt, qkvb, ROWS, QKVW, DMODEL);

  // chunked causal linear attention
  chunk_sums_mfma<<<dim3(NCH, NBH), 256, 0, stream>>>(qkvb, Sfrag);
  prefix_scan_frag<<<dim3(45, NBH), 64, 0, stream>>>(Sfrag, PG);
  attn_mfma<<<dim3(NCH, NBH), 256, 0, stream>>>(qkvb, PG, yb);

  // output projection (MFMA, fp32 out): 512 blocks = 2/CU
  gemm_mfma64<float><<<dim3(DMODEL / 128, ROWS / 64), 256, 0, stream>>>(
      yb, wot, out, ROWS, DMODEL, DMODEL);
}